// Round 12
// baseline (533.464 us; speedup 1.0000x reference)
//
#include <hip/hip_runtime.h>

#define N_NODES 100000
#define E_EDGES 1600000
#define E_TOT   1700000   // edges + self loops
#define FDIM    128       // F_IN and HEADS*HID
#define C2      10        // classes
#define YPAD    16        // yl/yr row stride (one 64B line)
#define NEG     0.2f
#define LOG2E   1.44269504088896f
#define PCLAMP  80.0f

#define NDEG    ((E_TOT + 255) / 256)        // 6641 edge chunks
#define NWT     128                          // 32768 / 256
#define GB4     ((N_NODES + 255) / 256)      // 391 gemm blocks (64 rows/wave)

typedef __attribute__((ext_vector_type(8))) short short8;
typedef __attribute__((ext_vector_type(4))) float f32x4;
typedef __attribute__((ext_vector_type(2))) float f32x2;

// 16-lane / 8-lane row reductions via DPP (pure VALU, no LDS pipe)
template <int CTRL>
__device__ __forceinline__ float dpp_add(float x) {
  return x + __int_as_float(
      __builtin_amdgcn_update_dpp(0, __float_as_int(x), CTRL, 0xF, 0xF, true));
}
__device__ __forceinline__ float row16_sum(float p) {
  p = dpp_add<0xB1>(p);
  p = dpp_add<0x4E>(p);
  p = dpp_add<0x141>(p);
  p = dpp_add<0x140>(p);
  return p;
}
__device__ __forceinline__ float row8_sum(float p) {
  p = dpp_add<0xB1>(p);
  p = dpp_add<0x4E>(p);
  p = dpp_add<0x141>(p);
  return p;
}

// fp32 -> bf16 (round-nearest-even), and packed bf16x2 -> float2
__device__ __forceinline__ unsigned short f2bf(float f) {
  unsigned int u = __float_as_uint(f);
  u += 0x7FFFu + ((u >> 16) & 1u);
  return (unsigned short)(u >> 16);
}
__device__ __forceinline__ f32x2 up2v(unsigned int v) {
  f32x2 r;
  r.x = __uint_as_float(v << 16);
  r.y = __uint_as_float(v & 0xFFFF0000u);
  return r;
}

#define SCAN_ITEMS 8
#define SCAN_CHUNK 2048
#define SCAN_NBLK  ((N_NODES + SCAN_CHUNK - 1) / SCAN_CHUNK)   // 49

// ---------------- W1 transpose + cnt zeroing + sync-var init ----------------
__global__ __launch_bounds__(256) void k_prep_w(const float* __restrict__ W1l, const float* __restrict__ W1r,
                                                unsigned short* __restrict__ Wt, int* __restrict__ cnt,
                                                int* __restrict__ agg, int* __restrict__ done) {
  int i = blockIdx.x * 256 + threadIdx.x;
  int n = i & 255, k = i >> 8;
  float v = (n < 128) ? W1l[k * 128 + n] : W1r[k * 128 + (n - 128)];
  Wt[n * 128 + k] = f2bf(v);   // B^T layout: row n, contiguous k
  for (int c = i; c < N_NODES; c += NWT * 256) cnt[c] = 0;
  if (blockIdx.x == 0 && threadIdx.x < 64) {
    if (threadIdx.x < SCAN_NBLK) agg[threadIdx.x] = -1;   // lookback sentinel
    if (threadIdx.x == 63) *done = 0;
  }
}

// ---------------- fused: degree count (blocks < NDEG, starts at t=0) + Layer-1 GEMM ----------------
// Register-blocked x4 gemm: one wave computes 64 rows; B-fragment feeds 16 MFMA.
__global__ __launch_bounds__(256) void k_gc(const float* __restrict__ x,
                                            const unsigned short* __restrict__ Wt,
                                            unsigned short* __restrict__ Hlb,
                                            unsigned short* __restrict__ Hrb,
                                            const int* __restrict__ ei, int* __restrict__ cnt,
                                            int* __restrict__ epos) {
  int b = blockIdx.x;
  if (b < NDEG) {
    int tid = b * 256 + threadIdx.x;
    if (tid < E_TOT) {
      int d = (tid < E_EDGES) ? ei[E_EDGES + tid] : (tid - E_EDGES);
      epos[tid] = atomicAdd(&cnt[d], 1);
    }
    return;
  }
  int gb = b - NDEG;
  int w = threadIdx.x >> 6, lane = threadIdx.x & 63;
  int m = lane & 15, quad = lane >> 4;
  int wrow0 = gb * 256 + w * 64;
  short8 A[4][4];   // [row-group][k-chunk]
#pragma unroll
  for (int g = 0; g < 4; g++) {
    int arow = wrow0 + g * 16 + m;
    bool aok = arow < N_NODES;
    const float4* ap = (const float4*)(x + (size_t)arow * FDIM + quad * 8);
#pragma unroll
    for (int c = 0; c < 4; c++) {
      short8 a = {};
      if (aok) {
        float4 v0 = ap[c * 8 + 0];
        float4 v1 = ap[c * 8 + 1];
        a[0] = (short)f2bf(v0.x); a[1] = (short)f2bf(v0.y);
        a[2] = (short)f2bf(v0.z); a[3] = (short)f2bf(v0.w);
        a[4] = (short)f2bf(v1.x); a[5] = (short)f2bf(v1.y);
        a[6] = (short)f2bf(v1.z); a[7] = (short)f2bf(v1.w);
      }
      A[g][c] = a;
    }
  }

#pragma unroll
  for (int t0 = 0; t0 < 16; t0++) {
    const short8* bp = (const short8*)(Wt + (size_t)(t0 * 16 + m) * 128 + quad * 8);
    short8 B0 = bp[0], B1 = bp[4], B2 = bp[8], B3 = bp[12];
    int n0 = t0 * 16;
    unsigned short* dst = (n0 < 128) ? Hlb : Hrb;
    int col = (n0 < 128) ? n0 + m : (n0 - 128) + m;
#pragma unroll
    for (int g = 0; g < 4; g++) {
      f32x4 acc = {0.f, 0.f, 0.f, 0.f};
      acc = __builtin_amdgcn_mfma_f32_16x16x32_bf16(A[g][0], B0, acc, 0, 0, 0);
      acc = __builtin_amdgcn_mfma_f32_16x16x32_bf16(A[g][1], B1, acc, 0, 0, 0);
      acc = __builtin_amdgcn_mfma_f32_16x16x32_bf16(A[g][2], B2, acc, 0, 0, 0);
      acc = __builtin_amdgcn_mfma_f32_16x16x32_bf16(A[g][3], B3, acc, 0, 0, 0);
      int orow = wrow0 + g * 16 + quad * 4;
#pragma unroll
      for (int r = 0; r < 4; r++) {
        int row = orow + r;
        if (row < N_NODES) dst[(size_t)row * FDIM + col] = f2bf(acc[r]);
      }
    }
  }
}

// ---------------- fused scan + scatter: blocks 0..48 scan (decoupled lookback), publish done;
// all NDEG blocks then scatter their edge chunk (atomic-free via epos). Publishers are
// dispatched first -> forward progress guaranteed (mechanism validated in r8's scan phase).
__global__ __launch_bounds__(256) void k_scsc(const int* __restrict__ cnt, const int* __restrict__ ei,
                                              const int* __restrict__ epos,
                                              int* __restrict__ row_ptr, int* __restrict__ colA,
                                              int* __restrict__ agg, int* __restrict__ done) {
  int b = blockIdx.x, t = threadIdx.x;
  if (b < SCAN_NBLK) {
    int base = b * SCAN_CHUNK + t * SCAN_ITEMS;
    int vals[SCAN_ITEMS]; int ts = 0;
#pragma unroll
    for (int i = 0; i < SCAN_ITEMS; i++) {
      int idx = base + i;
      vals[i] = (idx < N_NODES) ? cnt[idx] : 0;
      ts += vals[i];
    }
    __shared__ int sd[256];
    sd[t] = ts; __syncthreads();
    for (int o = 1; o < 256; o <<= 1) {
      int v = 0;
      if (t >= o) v = sd[t - o];
      __syncthreads();
      sd[t] += v;
      __syncthreads();
    }
    if (t == 0)
      __hip_atomic_store(&agg[b], sd[255], __ATOMIC_RELEASE, __HIP_MEMORY_SCOPE_AGENT);
    __shared__ int boffs;
    if (t < 64) {
      int v = 0;
      if (t < b) {
        while ((v = __hip_atomic_load(&agg[t], __ATOMIC_ACQUIRE, __HIP_MEMORY_SCOPE_AGENT)) < 0) {}
      }
      for (int o = 1; o < 64; o <<= 1) v += __shfl_xor(v, o);
      if (t == 0) boffs = v;
    }
    __syncthreads();
    int run = boffs + sd[t] - ts;
#pragma unroll
    for (int i = 0; i < SCAN_ITEMS; i++) {
      int idx = base + i;
      if (idx < N_NODES) row_ptr[idx] = run;
      run += vals[i];
    }
    if (b == 0 && t == 0) row_ptr[N_NODES] = E_TOT;
    __syncthreads();
    __threadfence();
    if (t == 0) __hip_atomic_fetch_add(done, 1, __ATOMIC_ACQ_REL, __HIP_MEMORY_SCOPE_AGENT);
  }
  if (t == 0) {
    while (__hip_atomic_load(done, __ATOMIC_ACQUIRE, __HIP_MEMORY_SCOPE_AGENT) < SCAN_NBLK) {}
  }
  __syncthreads();
  int tid = b * 256 + t;
  if (tid < E_TOT) {
    int s, d;
    if (tid < E_EDGES) { s = ei[tid]; d = ei[E_EDGES + tid]; }
    else { s = tid - E_EDGES; d = s; }
    colA[row_ptr[d] + epos[tid]] = s;
  }
}

// ---------------- Layer-1 aggregation + in-wave CSR sort + fused layer-2 transform ----------------
// r10 champion form exactly (plain w2t[132], blocked-half epilogue = measured 128.1 us).
__global__ __launch_bounds__(256) void k_agg1(const unsigned short* __restrict__ Hlb,
                                              const unsigned short* __restrict__ Hrb,
                                              const int* __restrict__ row_ptr, int* __restrict__ colA,
                                              const float* __restrict__ att, const float* __restrict__ bias,
                                              const float* __restrict__ W2l, const float* __restrict__ W2r,
                                              float* __restrict__ yl, float* __restrict__ yr) {
  __shared__ float hsh[4][FDIM];
  __shared__ int sidx[4][64];
  __shared__ float w2t[2][C2][132];   // transposed W2, +4 pad
  for (int i = threadIdx.x; i < FDIM * C2; i += 256) {
    int k = i / C2, cc = i - C2 * k;
    w2t[0][cc][k] = W2l[i];
    w2t[1][cc][k] = W2r[i];
  }
  __syncthreads();

  int w = threadIdx.x >> 6;
  int node = blockIdx.x * 4 + w;
  int lane = threadIdx.x & 63;
  int c0 = 2 * lane;
  const unsigned int* Hl32 = (const unsigned int*)Hlb;   // row = 64 uints
  const unsigned int* Hr32 = (const unsigned int*)Hrb;
  f32x2 xr = up2v(Hr32[((size_t)node << 6) + lane]);
  f32x2 av; av.x = att[c0] * LOG2E; av.y = att[c0 + 1] * LOG2E;
  int beg = row_ptr[node], end = row_ptr[node + 1];
  int deg = end - beg;
  bool small = deg <= 64;

  if (small) {
    // in-wave bitonic sort (canonical ascending order -> deterministic FP order)
    int v = (lane < deg) ? colA[beg + lane] : 0x7FFFFFFF;
#pragma unroll
    for (int k = 2; k <= 64; k <<= 1) {
#pragma unroll
      for (int j = k >> 1; j > 0; j >>= 1) {
        int other = __shfl_xor(v, j);
        bool up = ((lane & k) == 0);
        bool lower = ((lane & j) == 0);
        int mn = min(v, other), mx = max(v, other);
        v = (lower == up) ? mn : mx;
      }
    }
    sidx[w][lane] = v;                      // intra-wave: DS ops in order
    if (lane < deg) colA[beg + lane] = v;   // sorted row for agg2
  } else {
    if (lane == 0) {
      for (int i = beg + 1; i < end; i++) {
        int vv = colA[i];
        int j = i - 1;
        while (j >= beg && colA[j] > vv) { colA[j + 1] = colA[j]; j--; }
        colA[j + 1] = vv;
      }
    }
    __threadfence_block();
  }

  float l = 0.f;
  f32x2 acc = {0.f, 0.f};
  auto update = [&](unsigned int vv) {
    f32x2 xl = up2v(vv);
    f32x2 t = xl + xr;                       // v_pk_add_f32
    f32x2 u = t * NEG;                       // v_pk_mul_f32
    t = __builtin_elementwise_max(t, u);     // v_pk_max_f32: leaky = max(t, 0.2t)
    f32x2 m = t * av;                        // v_pk_mul_f32
    float p = row16_sum(m.x + m.y);
    float ww = __builtin_amdgcn_exp2f(fminf(p, PCLAMP));
    l += ww;
    acc += xl * ww;                          // v_pk_fma_f32
  };

  if (small) {
    const int* si = sidx[w];
    int j = 0;
    for (; j + 8 <= deg; j += 8) {
      unsigned int v0 = Hl32[((size_t)si[j + 0] << 6) + lane];
      unsigned int v1 = Hl32[((size_t)si[j + 1] << 6) + lane];
      unsigned int v2 = Hl32[((size_t)si[j + 2] << 6) + lane];
      unsigned int v3 = Hl32[((size_t)si[j + 3] << 6) + lane];
      unsigned int v4 = Hl32[((size_t)si[j + 4] << 6) + lane];
      unsigned int v5 = Hl32[((size_t)si[j + 5] << 6) + lane];
      unsigned int v6 = Hl32[((size_t)si[j + 6] << 6) + lane];
      unsigned int v7 = Hl32[((size_t)si[j + 7] << 6) + lane];
      update(v0); update(v1); update(v2); update(v3);
      update(v4); update(v5); update(v6); update(v7);
    }
    for (; j + 2 <= deg; j += 2) {
      unsigned int v0 = Hl32[((size_t)si[j + 0] << 6) + lane];
      unsigned int v1 = Hl32[((size_t)si[j + 1] << 6) + lane];
      update(v0); update(v1);
    }
    if (j < deg) update(Hl32[((size_t)si[j] << 6) + lane]);
  } else {
    for (int j = beg; j < end; j++) update(Hl32[((size_t)colA[j] << 6) + lane]);
  }

  float inv = 1.f / l;
  float ox = fmaxf(fmaf(acc.x, inv, bias[c0]),     0.f);   // fused ReLU
  float oy = fmaxf(fmaf(acc.y, inv, bias[c0 + 1]), 0.f);
  hsh[w][c0] = ox; hsh[w][c0 + 1] = oy;
  // epilogue: 2 lanes per output (lane 2o: k4 0..15, lane 2o+1: k4 16..31), shfl combine
  if (lane < 4 * C2) {
    int o = lane >> 1;               // output 0..19
    int half = lane & 1;             // k-range half
    bool isl = o < C2;
    int cc = isl ? o : o - C2;
    const float4* wrow = (const float4*)&w2t[isl ? 0 : 1][cc][0];
    const float4* h4 = (const float4*)hsh[w];
    float a2 = 0.f;
    int k0 = half << 4;
#pragma unroll
    for (int k4 = 0; k4 < 16; k4++) {
      float4 hv = h4[k0 + k4];
      float4 wv = wrow[k0 + k4];
      a2 = fmaf(hv.x, wv.x, a2);
      a2 = fmaf(hv.y, wv.y, a2);
      a2 = fmaf(hv.z, wv.z, a2);
      a2 = fmaf(hv.w, wv.w, a2);
    }
    a2 += __shfl_xor(a2, 1);         // fixed tree: (low half)+(high half)
    if (half == 0) {
      float* Y = isl ? yl : yr;
      Y[(size_t)node * YPAD + cc] = a2;
    }
  }
}

// ---------------- Layer-2 aggregation: 1 wave/node, 8-way edge-parallel, 2 ch/lane packed ----------------
__global__ __launch_bounds__(256) void k_agg2(const float* __restrict__ yl, const float* __restrict__ yr,
                                              const int* __restrict__ row_ptr, const int* __restrict__ colA,
                                              const float* __restrict__ att, const float* __restrict__ bias,
                                              float* __restrict__ outp) {
  int w = threadIdx.x >> 6;
  int node = blockIdx.x * 4 + w;
  if (node >= N_NODES) return;
  int lane = threadIdx.x & 63;
  int ch = 2 * (lane & 7);     // channel pair this lane owns
  int g  = lane >> 3;          // edge-group 0..7
  bool act = ch < C2;
  f32x2 xr = {0.f, 0.f};
  f32x2 a2 = {0.f, 0.f};
  if (act) {
    const float2* yr2 = (const float2*)(yr + (size_t)node * YPAD);
    float2 t = yr2[lane & 7];
    xr.x = t.x; xr.y = t.y;
    a2.x = att[ch] * LOG2E; a2.y = att[ch + 1] * LOG2E;
  }
  int beg = row_ptr[node], end = row_ptr[node + 1];
  float l = 0.f;
  f32x2 acc = {0.f, 0.f};
  const float2* ylL = (const float2*)yl + (lane & 7);   // row s at (s<<3) float2 units

  auto update = [&](f32x2 xl) {
    f32x2 t = xl + xr;                       // v_pk_add_f32
    f32x2 u = t * NEG;                       // v_pk_mul_f32
    t = __builtin_elementwise_max(t, u);     // v_pk_max_f32
    f32x2 m = t * a2;                        // v_pk_mul_f32
    float p = row8_sum(m.x + m.y);           // 8-lane group reduce (inactive lanes add 0)
    float wgt = __builtin_amdgcn_exp2f(fminf(p, PCLAMP));
    l += wgt;
    acc += xl * wgt;                         // v_pk_fma_f32
  };
  auto load = [&](int s) -> f32x2 {
    f32x2 r = {0.f, 0.f};
    if (act) {
      float2 t = ylL[(size_t)s << 3];        // yl row stride 16 floats = 8 float2
      r.x = t.x; r.y = t.y;
    }
    return r;
  };

  int j = beg + g;
  for (; j + 8 < end; j += 16) {             // 2 edges of this group: j, j+8
    int s0 = colA[j], s1 = colA[j + 8];
    f32x2 x0 = load(s0), x1 = load(s1);
    update(x0); update(x1);
  }
  if (j < end) update(load(colA[j]));

  // fixed combine tree across the 8 groups (deterministic)
  for (int o = 8; o <= 32; o <<= 1) {
    l     += __shfl_xor(l, o);
    acc.x += __shfl_xor(acc.x, o);
    acc.y += __shfl_xor(acc.y, o);
  }
  if (g == 0 && act) {
    float2 o;
    o.x = acc.x / l + bias[ch];
    o.y = acc.y / l + bias[ch + 1];
    *(float2*)(outp + (size_t)node * C2 + ch) = o;
  }
}

extern "C" void kernel_launch(void* const* d_in, const int* in_sizes, int n_in,
                              void* d_out, int out_size, void* d_ws, size_t ws_size,
                              hipStream_t stream) {
  const float* x    = (const float*)d_in[0];
  const int*   ei   = (const int*)d_in[1];
  const float* W1l  = (const float*)d_in[2];
  const float* W1r  = (const float*)d_in[3];
  const float* att1 = (const float*)d_in[4];
  const float* b1   = (const float*)d_in[5];
  const float* W2l  = (const float*)d_in[6];
  const float* W2r  = (const float*)d_in[7];
  const float* att2 = (const float*)d_in[8];
  const float* b2   = (const float*)d_in[9];
  float* out = (float*)d_out;

  char* ws = (char*)d_ws;
  size_t off = 0;
  auto take = [&](size_t bytes) -> char* {
    char* p = ws + off;
    off = (off + bytes + 511) & ~(size_t)511;
    return p;
  };
  unsigned short* Hlb = (unsigned short*)take((size_t)N_NODES * FDIM * sizeof(unsigned short)); // 25.6 MB
  unsigned short* Hrb = (unsigned short*)take((size_t)N_NODES * FDIM * sizeof(unsigned short)); // 25.6 MB
  unsigned short* Wt  = (unsigned short*)take((size_t)256 * 128 * sizeof(unsigned short));      // 64 KB
  float* yl      = (float*)take((size_t)N_NODES * YPAD * sizeof(float));   // 6.4 MB
  float* yr      = (float*)take((size_t)N_NODES * YPAD * sizeof(float));   // 6.4 MB
  int*   cnt     = (int*)take((size_t)N_NODES * sizeof(int));
  int*   row_ptr = (int*)take((size_t)(N_NODES + 1) * sizeof(int));
  int*   colA    = (int*)take((size_t)E_TOT * sizeof(int));
  int*   epos    = (int*)take((size_t)E_TOT * sizeof(int));
  int*   agg     = (int*)take(256);
  int*   done    = (int*)take(256);
  if (off > ws_size) return;

  k_prep_w <<<NWT, 256, 0, stream>>>(W1l, W1r, Wt, cnt, agg, done);
  k_gc     <<<NDEG + GB4, 256, 0, stream>>>(x, Wt, Hlb, Hrb, ei, cnt, epos);
  k_scsc   <<<NDEG, 256, 0, stream>>>(cnt, ei, epos, row_ptr, colA, agg, done);
  k_agg1   <<<(N_NODES + 3) / 4, 256, 0, stream>>>(Hlb, Hrb, row_ptr, colA, att1, b1, W2l, W2r, yl, yr);
  k_agg2   <<<(N_NODES + 3) / 4, 256, 0, stream>>>(yl, yr, row_ptr, colA, att2, b2, out);
}

// Round 13
// 415.103 us; speedup vs baseline: 1.2851x; 1.2851x over previous
//
#include <hip/hip_runtime.h>

#define N_NODES 100000
#define E_EDGES 1600000
#define E_TOT   1700000   // edges + self loops
#define FDIM    128       // F_IN and HEADS*HID
#define C2      10        // classes
#define YPAD    16        // yl/yr row stride (one 64B line)
#define NEG     0.2f
#define LOG2E   1.44269504088896f
#define PCLAMP  80.0f

#define NDEG    ((E_TOT + 255) / 256)        // 6641 edge chunks
#define NWT     128                          // 32768 / 256
#define GB4     ((N_NODES + 255) / 256)      // 391 gemm blocks (64 rows/wave)

typedef __attribute__((ext_vector_type(8))) short short8;
typedef __attribute__((ext_vector_type(4))) float f32x4;
typedef __attribute__((ext_vector_type(2))) float f32x2;

// 16-lane / 8-lane row reductions via DPP (pure VALU, no LDS pipe)
template <int CTRL>
__device__ __forceinline__ float dpp_add(float x) {
  return x + __int_as_float(
      __builtin_amdgcn_update_dpp(0, __float_as_int(x), CTRL, 0xF, 0xF, true));
}
__device__ __forceinline__ float row16_sum(float p) {
  p = dpp_add<0xB1>(p);
  p = dpp_add<0x4E>(p);
  p = dpp_add<0x141>(p);
  p = dpp_add<0x140>(p);
  return p;
}
__device__ __forceinline__ float row8_sum(float p) {
  p = dpp_add<0xB1>(p);
  p = dpp_add<0x4E>(p);
  p = dpp_add<0x141>(p);
  return p;
}

// fp32 -> bf16 (round-nearest-even), and packed bf16x2 -> float2
__device__ __forceinline__ unsigned short f2bf(float f) {
  unsigned int u = __float_as_uint(f);
  u += 0x7FFFu + ((u >> 16) & 1u);
  return (unsigned short)(u >> 16);
}
__device__ __forceinline__ f32x2 up2v(unsigned int v) {
  f32x2 r;
  r.x = __uint_as_float(v << 16);
  r.y = __uint_as_float(v & 0xFFFF0000u);
  return r;
}

#define SCAN_ITEMS 8
#define SCAN_CHUNK 2048
#define SCAN_NBLK  ((N_NODES + SCAN_CHUNK - 1) / SCAN_CHUNK)   // 49

// ---------------- W1 transpose + cnt zeroing + scan-lookback init ----------------
__global__ __launch_bounds__(256) void k_prep_w(const float* __restrict__ W1l, const float* __restrict__ W1r,
                                                unsigned short* __restrict__ Wt, int* __restrict__ cnt,
                                                int* __restrict__ agg) {
  int i = blockIdx.x * 256 + threadIdx.x;
  int n = i & 255, k = i >> 8;
  float v = (n < 128) ? W1l[k * 128 + n] : W1r[k * 128 + (n - 128)];
  Wt[n * 128 + k] = f2bf(v);   // B^T layout: row n, contiguous k
  for (int c = i; c < N_NODES; c += NWT * 256) cnt[c] = 0;
  if (blockIdx.x == 0 && threadIdx.x < SCAN_NBLK) agg[threadIdx.x] = -1;   // lookback sentinel
}

// ---------------- fused: Layer-1 GEMM (blocks < GB4) + degree count (rest) ----------------
// Register-blocked x4: one wave computes 64 rows; each B-fragment feeds 16 MFMA.
__global__ __launch_bounds__(256) void k_gc(const float* __restrict__ x,
                                            const unsigned short* __restrict__ Wt,
                                            unsigned short* __restrict__ Hlb,
                                            unsigned short* __restrict__ Hrb,
                                            const int* __restrict__ ei, int* __restrict__ cnt,
                                            int* __restrict__ epos) {
  int b = blockIdx.x;
  if (b >= GB4) {
    int tid = (b - GB4) * 256 + threadIdx.x;
    if (tid < E_TOT) {
      int d = (tid < E_EDGES) ? ei[E_EDGES + tid] : (tid - E_EDGES);
      epos[tid] = atomicAdd(&cnt[d], 1);
    }
    return;
  }
  int w = threadIdx.x >> 6, lane = threadIdx.x & 63;
  int m = lane & 15, quad = lane >> 4;
  int wrow0 = b * 256 + w * 64;
  short8 A[4][4];   // [row-group][k-chunk]
#pragma unroll
  for (int g = 0; g < 4; g++) {
    int arow = wrow0 + g * 16 + m;
    bool aok = arow < N_NODES;
    const float4* ap = (const float4*)(x + (size_t)arow * FDIM + quad * 8);
#pragma unroll
    for (int c = 0; c < 4; c++) {
      short8 a = {};
      if (aok) {
        float4 v0 = ap[c * 8 + 0];
        float4 v1 = ap[c * 8 + 1];
        a[0] = (short)f2bf(v0.x); a[1] = (short)f2bf(v0.y);
        a[2] = (short)f2bf(v0.z); a[3] = (short)f2bf(v0.w);
        a[4] = (short)f2bf(v1.x); a[5] = (short)f2bf(v1.y);
        a[6] = (short)f2bf(v1.z); a[7] = (short)f2bf(v1.w);
      }
      A[g][c] = a;
    }
  }

#pragma unroll
  for (int t0 = 0; t0 < 16; t0++) {
    const short8* bp = (const short8*)(Wt + (size_t)(t0 * 16 + m) * 128 + quad * 8);
    short8 B0 = bp[0], B1 = bp[4], B2 = bp[8], B3 = bp[12];
    int n0 = t0 * 16;
    unsigned short* dst = (n0 < 128) ? Hlb : Hrb;
    int col = (n0 < 128) ? n0 + m : (n0 - 128) + m;
#pragma unroll
    for (int g = 0; g < 4; g++) {
      f32x4 acc = {0.f, 0.f, 0.f, 0.f};
      acc = __builtin_amdgcn_mfma_f32_16x16x32_bf16(A[g][0], B0, acc, 0, 0, 0);
      acc = __builtin_amdgcn_mfma_f32_16x16x32_bf16(A[g][1], B1, acc, 0, 0, 0);
      acc = __builtin_amdgcn_mfma_f32_16x16x32_bf16(A[g][2], B2, acc, 0, 0, 0);
      acc = __builtin_amdgcn_mfma_f32_16x16x32_bf16(A[g][3], B3, acc, 0, 0, 0);
      int orow = wrow0 + g * 16 + quad * 4;
#pragma unroll
      for (int r = 0; r < 4; r++) {
        int row = orow + r;
        if (row < N_NODES) dst[(size_t)row * FDIM + col] = f2bf(acc[r]);
      }
    }
  }
}

// ---------------- fused scan: per-chunk scan + decoupled lookback (49 blocks only) ----------------
__global__ __launch_bounds__(256) void k_scan(const int* __restrict__ cnt, int* __restrict__ row_ptr,
                                              int* __restrict__ agg) {
  int b = blockIdx.x, t = threadIdx.x;
  int base = b * SCAN_CHUNK + t * SCAN_ITEMS;
  int vals[SCAN_ITEMS]; int ts = 0;
#pragma unroll
  for (int i = 0; i < SCAN_ITEMS; i++) {
    int idx = base + i;
    vals[i] = (idx < N_NODES) ? cnt[idx] : 0;
    ts += vals[i];
  }
  __shared__ int sd[256];
  sd[t] = ts; __syncthreads();
  for (int o = 1; o < 256; o <<= 1) {
    int v = 0;
    if (t >= o) v = sd[t - o];
    __syncthreads();
    sd[t] += v;
    __syncthreads();
  }
  if (t == 0)
    __hip_atomic_store(&agg[b], sd[255], __ATOMIC_RELEASE, __HIP_MEMORY_SCOPE_AGENT);
  __shared__ int boffs;
  if (t < 64) {
    int v = 0;
    if (t < b) {   // b <= 48 < 64: one wave covers the full prefix
      while ((v = __hip_atomic_load(&agg[t], __ATOMIC_ACQUIRE, __HIP_MEMORY_SCOPE_AGENT)) < 0) {}
    }
    for (int o = 1; o < 64; o <<= 1) v += __shfl_xor(v, o);
    if (t == 0) boffs = v;
  }
  __syncthreads();
  int run = boffs + sd[t] - ts;
#pragma unroll
  for (int i = 0; i < SCAN_ITEMS; i++) {
    int idx = base + i;
    if (idx < N_NODES) row_ptr[idx] = run;
    run += vals[i];
  }
  if (b == 0 && t == 0) row_ptr[N_NODES] = E_TOT;
}

__global__ __launch_bounds__(256) void k_scatter(const int* __restrict__ ei,
                                                 const int* __restrict__ row_ptr,
                                                 const int* __restrict__ epos,
                                                 int* __restrict__ colA) {
  int tid = blockIdx.x * 256 + threadIdx.x;
  if (tid >= E_TOT) return;
  int s, d;
  if (tid < E_EDGES) { s = ei[tid]; d = ei[E_EDGES + tid]; }
  else { s = tid - E_EDGES; d = s; }
  colA[row_ptr[d] + epos[tid]] = s;
}

// ---------------- Layer-1 aggregation + in-wave CSR sort + fused layer-2 transform ----------------
// r10 champion form exactly (plain w2t[132], half-split epilogue = measured 128.1 us).
__global__ __launch_bounds__(256) void k_agg1(const unsigned short* __restrict__ Hlb,
                                              const unsigned short* __restrict__ Hrb,
                                              const int* __restrict__ row_ptr, int* __restrict__ colA,
                                              const float* __restrict__ att, const float* __restrict__ bias,
                                              const float* __restrict__ W2l, const float* __restrict__ W2r,
                                              float* __restrict__ yl, float* __restrict__ yr) {
  __shared__ float hsh[4][FDIM];
  __shared__ int sidx[4][64];
  __shared__ float w2t[2][C2][132];   // transposed W2, +4 pad
  for (int i = threadIdx.x; i < FDIM * C2; i += 256) {
    int k = i / C2, cc = i - C2 * k;
    w2t[0][cc][k] = W2l[i];
    w2t[1][cc][k] = W2r[i];
  }
  __syncthreads();

  int w = threadIdx.x >> 6;
  int node = blockIdx.x * 4 + w;
  int lane = threadIdx.x & 63;
  int c0 = 2 * lane;
  const unsigned int* Hl32 = (const unsigned int*)Hlb;   // row = 64 uints
  const unsigned int* Hr32 = (const unsigned int*)Hrb;
  f32x2 xr = up2v(Hr32[((size_t)node << 6) + lane]);
  f32x2 av; av.x = att[c0] * LOG2E; av.y = att[c0 + 1] * LOG2E;
  int beg = row_ptr[node], end = row_ptr[node + 1];
  int deg = end - beg;
  bool small = deg <= 64;

  if (small) {
    // in-wave bitonic sort (canonical ascending order -> deterministic FP order)
    int v = (lane < deg) ? colA[beg + lane] : 0x7FFFFFFF;
#pragma unroll
    for (int k = 2; k <= 64; k <<= 1) {
#pragma unroll
      for (int j = k >> 1; j > 0; j >>= 1) {
        int other = __shfl_xor(v, j);
        bool up = ((lane & k) == 0);
        bool lower = ((lane & j) == 0);
        int mn = min(v, other), mx = max(v, other);
        v = (lower == up) ? mn : mx;
      }
    }
    sidx[w][lane] = v;                      // intra-wave: DS ops in order
    if (lane < deg) colA[beg + lane] = v;   // sorted row for agg2
  } else {
    if (lane == 0) {
      for (int i = beg + 1; i < end; i++) {
        int vv = colA[i];
        int j = i - 1;
        while (j >= beg && colA[j] > vv) { colA[j + 1] = colA[j]; j--; }
        colA[j + 1] = vv;
      }
    }
    __threadfence_block();
  }

  float l = 0.f;
  f32x2 acc = {0.f, 0.f};
  auto update = [&](unsigned int vv) {
    f32x2 xl = up2v(vv);
    f32x2 t = xl + xr;                       // v_pk_add_f32
    f32x2 u = t * NEG;                       // v_pk_mul_f32
    t = __builtin_elementwise_max(t, u);     // v_pk_max_f32: leaky = max(t, 0.2t)
    f32x2 m = t * av;                        // v_pk_mul_f32
    float p = row16_sum(m.x + m.y);
    float ww = __builtin_amdgcn_exp2f(fminf(p, PCLAMP));
    l += ww;
    acc += xl * ww;                          // v_pk_fma_f32
  };

  if (small) {
    const int* si = sidx[w];
    int j = 0;
    for (; j + 8 <= deg; j += 8) {
      unsigned int v0 = Hl32[((size_t)si[j + 0] << 6) + lane];
      unsigned int v1 = Hl32[((size_t)si[j + 1] << 6) + lane];
      unsigned int v2 = Hl32[((size_t)si[j + 2] << 6) + lane];
      unsigned int v3 = Hl32[((size_t)si[j + 3] << 6) + lane];
      unsigned int v4 = Hl32[((size_t)si[j + 4] << 6) + lane];
      unsigned int v5 = Hl32[((size_t)si[j + 5] << 6) + lane];
      unsigned int v6 = Hl32[((size_t)si[j + 6] << 6) + lane];
      unsigned int v7 = Hl32[((size_t)si[j + 7] << 6) + lane];
      update(v0); update(v1); update(v2); update(v3);
      update(v4); update(v5); update(v6); update(v7);
    }
    for (; j + 2 <= deg; j += 2) {
      unsigned int v0 = Hl32[((size_t)si[j + 0] << 6) + lane];
      unsigned int v1 = Hl32[((size_t)si[j + 1] << 6) + lane];
      update(v0); update(v1);
    }
    if (j < deg) update(Hl32[((size_t)si[j] << 6) + lane]);
  } else {
    for (int j = beg; j < end; j++) update(Hl32[((size_t)colA[j] << 6) + lane]);
  }

  float inv = 1.f / l;
  float ox = fmaxf(fmaf(acc.x, inv, bias[c0]),     0.f);   // fused ReLU
  float oy = fmaxf(fmaf(acc.y, inv, bias[c0 + 1]), 0.f);
  hsh[w][c0] = ox; hsh[w][c0 + 1] = oy;
  // epilogue: 2 lanes per output (lane 2o: k4 0..15, lane 2o+1: k4 16..31), shfl combine
  if (lane < 4 * C2) {
    int o = lane >> 1;               // output 0..19
    int half = lane & 1;             // k-range half
    bool isl = o < C2;
    int cc = isl ? o : o - C2;
    const float4* wrow = (const float4*)&w2t[isl ? 0 : 1][cc][0];
    const float4* h4 = (const float4*)hsh[w];
    float a2 = 0.f;
    int k0 = half << 4;
#pragma unroll
    for (int k4 = 0; k4 < 16; k4++) {
      float4 hv = h4[k0 + k4];
      float4 wv = wrow[k0 + k4];
      a2 = fmaf(hv.x, wv.x, a2);
      a2 = fmaf(hv.y, wv.y, a2);
      a2 = fmaf(hv.z, wv.z, a2);
      a2 = fmaf(hv.w, wv.w, a2);
    }
    a2 += __shfl_xor(a2, 1);         // fixed tree: (low half)+(high half)
    if (half == 0) {
      float* Y = isl ? yl : yr;
      Y[(size_t)node * YPAD + cc] = a2;
    }
  }
}

// ---------------- Layer-2 aggregation: 1 wave/node, 8-way edge-parallel, 2 ch/lane packed ----------------
__global__ __launch_bounds__(256) void k_agg2(const float* __restrict__ yl, const float* __restrict__ yr,
                                              const int* __restrict__ row_ptr, const int* __restrict__ colA,
                                              const float* __restrict__ att, const float* __restrict__ bias,
                                              float* __restrict__ outp) {
  int w = threadIdx.x >> 6;
  int node = blockIdx.x * 4 + w;
  if (node >= N_NODES) return;
  int lane = threadIdx.x & 63;
  int ch = 2 * (lane & 7);     // channel pair this lane owns
  int g  = lane >> 3;          // edge-group 0..7
  bool act = ch < C2;
  f32x2 xr = {0.f, 0.f};
  f32x2 a2 = {0.f, 0.f};
  if (act) {
    const float2* yr2 = (const float2*)(yr + (size_t)node * YPAD);
    float2 t = yr2[lane & 7];
    xr.x = t.x; xr.y = t.y;
    a2.x = att[ch] * LOG2E; a2.y = att[ch + 1] * LOG2E;
  }
  int beg = row_ptr[node], end = row_ptr[node + 1];
  float l = 0.f;
  f32x2 acc = {0.f, 0.f};
  const float2* ylL = (const float2*)yl + (lane & 7);   // row s at (s<<3) float2 units

  auto update = [&](f32x2 xl) {
    f32x2 t = xl + xr;                       // v_pk_add_f32
    f32x2 u = t * NEG;                       // v_pk_mul_f32
    t = __builtin_elementwise_max(t, u);     // v_pk_max_f32
    f32x2 m = t * a2;                        // v_pk_mul_f32
    float p = row8_sum(m.x + m.y);           // 8-lane group reduce (inactive lanes add 0)
    float wgt = __builtin_amdgcn_exp2f(fminf(p, PCLAMP));
    l += wgt;
    acc += xl * wgt;                         // v_pk_fma_f32
  };
  auto load = [&](int s) -> f32x2 {
    f32x2 r = {0.f, 0.f};
    if (act) {
      float2 t = ylL[(size_t)s << 3];        // yl row stride 16 floats = 8 float2
      r.x = t.x; r.y = t.y;
    }
    return r;
  };

  int j = beg + g;
  for (; j + 8 < end; j += 16) {             // 2 edges of this group: j, j+8
    int s0 = colA[j], s1 = colA[j + 8];
    f32x2 x0 = load(s0), x1 = load(s1);
    update(x0); update(x1);
  }
  if (j < end) update(load(colA[j]));

  // fixed combine tree across the 8 groups (deterministic)
  for (int o = 8; o <= 32; o <<= 1) {
    l     += __shfl_xor(l, o);
    acc.x += __shfl_xor(acc.x, o);
    acc.y += __shfl_xor(acc.y, o);
  }
  if (g == 0 && act) {
    float2 o;
    o.x = acc.x / l + bias[ch];
    o.y = acc.y / l + bias[ch + 1];
    *(float2*)(outp + (size_t)node * C2 + ch) = o;
  }
}

extern "C" void kernel_launch(void* const* d_in, const int* in_sizes, int n_in,
                              void* d_out, int out_size, void* d_ws, size_t ws_size,
                              hipStream_t stream) {
  const float* x    = (const float*)d_in[0];
  const int*   ei   = (const int*)d_in[1];
  const float* W1l  = (const float*)d_in[2];
  const float* W1r  = (const float*)d_in[3];
  const float* att1 = (const float*)d_in[4];
  const float* b1   = (const float*)d_in[5];
  const float* W2l  = (const float*)d_in[6];
  const float* W2r  = (const float*)d_in[7];
  const float* att2 = (const float*)d_in[8];
  const float* b2   = (const float*)d_in[9];
  float* out = (float*)d_out;

  char* ws = (char*)d_ws;
  size_t off = 0;
  auto take = [&](size_t bytes) -> char* {
    char* p = ws + off;
    off = (off + bytes + 511) & ~(size_t)511;
    return p;
  };
  unsigned short* Hlb = (unsigned short*)take((size_t)N_NODES * FDIM * sizeof(unsigned short)); // 25.6 MB
  unsigned short* Hrb = (unsigned short*)take((size_t)N_NODES * FDIM * sizeof(unsigned short)); // 25.6 MB
  unsigned short* Wt  = (unsigned short*)take((size_t)256 * 128 * sizeof(unsigned short));      // 64 KB
  float* yl      = (float*)take((size_t)N_NODES * YPAD * sizeof(float));   // 6.4 MB
  float* yr      = (float*)take((size_t)N_NODES * YPAD * sizeof(float));   // 6.4 MB
  int*   cnt     = (int*)take((size_t)N_NODES * sizeof(int));
  int*   row_ptr = (int*)take((size_t)(N_NODES + 1) * sizeof(int));
  int*   colA    = (int*)take((size_t)E_TOT * sizeof(int));
  int*   epos    = (int*)take((size_t)E_TOT * sizeof(int));
  int*   agg     = (int*)take(256);
  if (off > ws_size) return;

  k_prep_w <<<NWT, 256, 0, stream>>>(W1l, W1r, Wt, cnt, agg);
  k_gc     <<<GB4 + NDEG, 256, 0, stream>>>(x, Wt, Hlb, Hrb, ei, cnt, epos);
  k_scan   <<<SCAN_NBLK, 256, 0, stream>>>(cnt, row_ptr, agg);
  k_scatter<<<(E_TOT + 255) / 256, 256, 0, stream>>>(ei, row_ptr, epos, colA);
  k_agg1   <<<(N_NODES + 3) / 4, 256, 0, stream>>>(Hlb, Hrb, row_ptr, colA, att1, b1, W2l, W2r, yl, yr);
  k_agg2   <<<(N_NODES + 3) / 4, 256, 0, stream>>>(yl, yr, row_ptr, colA, att2, b2, out);
}

// Round 14
// 404.584 us; speedup vs baseline: 1.3185x; 1.0260x over previous
//
#include <hip/hip_runtime.h>

#define N_NODES 100000
#define E_EDGES 1600000
#define E_TOT   1700000   // edges + self loops
#define FDIM    128       // F_IN and HEADS*HID
#define C2      10        // classes
#define YPAD    16        // yl/yr row stride (one 64B line)
#define NEG     0.2f
#define LOG2E   1.44269504088896f
#define PCLAMP  80.0f

#define NDEG    ((E_TOT + 255) / 256)        // 6641 edge chunks
#define NWT     128                          // 32768 / 256
#define GB4     ((N_NODES + 255) / 256)      // 391 gemm blocks (64 rows/wave)

typedef __attribute__((ext_vector_type(8))) short short8;
typedef __attribute__((ext_vector_type(4))) float f32x4;
typedef __attribute__((ext_vector_type(2))) float f32x2;

// 16-lane / 8-lane row reductions via DPP (pure VALU, no LDS pipe)
template <int CTRL>
__device__ __forceinline__ float dpp_add(float x) {
  return x + __int_as_float(
      __builtin_amdgcn_update_dpp(0, __float_as_int(x), CTRL, 0xF, 0xF, true));
}
__device__ __forceinline__ float row16_sum(float p) {
  p = dpp_add<0xB1>(p);
  p = dpp_add<0x4E>(p);
  p = dpp_add<0x141>(p);
  p = dpp_add<0x140>(p);
  return p;
}
__device__ __forceinline__ float row8_sum(float p) {
  p = dpp_add<0xB1>(p);
  p = dpp_add<0x4E>(p);
  p = dpp_add<0x141>(p);
  return p;
}

// fp32 -> bf16 (round-nearest-even), and packed bf16x2 -> float2
__device__ __forceinline__ unsigned short f2bf(float f) {
  unsigned int u = __float_as_uint(f);
  u += 0x7FFFu + ((u >> 16) & 1u);
  return (unsigned short)(u >> 16);
}
__device__ __forceinline__ f32x2 up2v(unsigned int v) {
  f32x2 r;
  r.x = __uint_as_float(v << 16);
  r.y = __uint_as_float(v & 0xFFFF0000u);
  return r;
}

#define SCAN_ITEMS 8
#define SCAN_CHUNK 2048
#define SCAN_NBLK  ((N_NODES + SCAN_CHUNK - 1) / SCAN_CHUNK)   // 49

// ---------------- W1 transpose + cnt zeroing + scan-lookback init ----------------
__global__ __launch_bounds__(256) void k_prep_w(const float* __restrict__ W1l, const float* __restrict__ W1r,
                                                unsigned short* __restrict__ Wt, int* __restrict__ cnt,
                                                int* __restrict__ agg) {
  int i = blockIdx.x * 256 + threadIdx.x;
  int n = i & 255, k = i >> 8;
  float v = (n < 128) ? W1l[k * 128 + n] : W1r[k * 128 + (n - 128)];
  Wt[n * 128 + k] = f2bf(v);   // B^T layout: row n, contiguous k
  for (int c = i; c < N_NODES; c += NWT * 256) cnt[c] = 0;
  if (blockIdx.x == 0 && threadIdx.x < SCAN_NBLK) agg[threadIdx.x] = -1;   // lookback sentinel
}

// ---------------- fused: Layer-1 GEMM (blocks < GB4) + degree count (rest) ----------------
// Register-blocked x4: one wave computes 64 rows; each B-fragment feeds 16 MFMA.
// epos stored as ushort (max degree << 65536): halves count-phase store traffic.
__global__ __launch_bounds__(256) void k_gc(const float* __restrict__ x,
                                            const unsigned short* __restrict__ Wt,
                                            unsigned short* __restrict__ Hlb,
                                            unsigned short* __restrict__ Hrb,
                                            const int* __restrict__ ei, int* __restrict__ cnt,
                                            unsigned short* __restrict__ epos) {
  int b = blockIdx.x;
  if (b >= GB4) {
    int tid = (b - GB4) * 256 + threadIdx.x;
    if (tid < E_TOT) {
      int d = (tid < E_EDGES) ? ei[E_EDGES + tid] : (tid - E_EDGES);
      epos[tid] = (unsigned short)atomicAdd(&cnt[d], 1);
    }
    return;
  }
  int w = threadIdx.x >> 6, lane = threadIdx.x & 63;
  int m = lane & 15, quad = lane >> 4;
  int wrow0 = b * 256 + w * 64;
  short8 A[4][4];   // [row-group][k-chunk]
#pragma unroll
  for (int g = 0; g < 4; g++) {
    int arow = wrow0 + g * 16 + m;
    bool aok = arow < N_NODES;
    const float4* ap = (const float4*)(x + (size_t)arow * FDIM + quad * 8);
#pragma unroll
    for (int c = 0; c < 4; c++) {
      short8 a = {};
      if (aok) {
        float4 v0 = ap[c * 8 + 0];
        float4 v1 = ap[c * 8 + 1];
        a[0] = (short)f2bf(v0.x); a[1] = (short)f2bf(v0.y);
        a[2] = (short)f2bf(v0.z); a[3] = (short)f2bf(v0.w);
        a[4] = (short)f2bf(v1.x); a[5] = (short)f2bf(v1.y);
        a[6] = (short)f2bf(v1.z); a[7] = (short)f2bf(v1.w);
      }
      A[g][c] = a;
    }
  }

#pragma unroll
  for (int t0 = 0; t0 < 16; t0++) {
    const short8* bp = (const short8*)(Wt + (size_t)(t0 * 16 + m) * 128 + quad * 8);
    short8 B0 = bp[0], B1 = bp[4], B2 = bp[8], B3 = bp[12];
    int n0 = t0 * 16;
    unsigned short* dst = (n0 < 128) ? Hlb : Hrb;
    int col = (n0 < 128) ? n0 + m : (n0 - 128) + m;
#pragma unroll
    for (int g = 0; g < 4; g++) {
      f32x4 acc = {0.f, 0.f, 0.f, 0.f};
      acc = __builtin_amdgcn_mfma_f32_16x16x32_bf16(A[g][0], B0, acc, 0, 0, 0);
      acc = __builtin_amdgcn_mfma_f32_16x16x32_bf16(A[g][1], B1, acc, 0, 0, 0);
      acc = __builtin_amdgcn_mfma_f32_16x16x32_bf16(A[g][2], B2, acc, 0, 0, 0);
      acc = __builtin_amdgcn_mfma_f32_16x16x32_bf16(A[g][3], B3, acc, 0, 0, 0);
      int orow = wrow0 + g * 16 + quad * 4;
#pragma unroll
      for (int r = 0; r < 4; r++) {
        int row = orow + r;
        if (row < N_NODES) dst[(size_t)row * FDIM + col] = f2bf(acc[r]);
      }
    }
  }
}

// ---------------- fused scan: per-chunk scan + decoupled lookback (49 blocks only) ----------------
__global__ __launch_bounds__(256) void k_scan(const int* __restrict__ cnt, int* __restrict__ row_ptr,
                                              int* __restrict__ agg) {
  int b = blockIdx.x, t = threadIdx.x;
  int base = b * SCAN_CHUNK + t * SCAN_ITEMS;
  int vals[SCAN_ITEMS]; int ts = 0;
#pragma unroll
  for (int i = 0; i < SCAN_ITEMS; i++) {
    int idx = base + i;
    vals[i] = (idx < N_NODES) ? cnt[idx] : 0;
    ts += vals[i];
  }
  __shared__ int sd[256];
  sd[t] = ts; __syncthreads();
  for (int o = 1; o < 256; o <<= 1) {
    int v = 0;
    if (t >= o) v = sd[t - o];
    __syncthreads();
    sd[t] += v;
    __syncthreads();
  }
  if (t == 0)
    __hip_atomic_store(&agg[b], sd[255], __ATOMIC_RELEASE, __HIP_MEMORY_SCOPE_AGENT);
  __shared__ int boffs;
  if (t < 64) {
    int v = 0;
    if (t < b) {   // b <= 48 < 64: one wave covers the full prefix
      while ((v = __hip_atomic_load(&agg[t], __ATOMIC_ACQUIRE, __HIP_MEMORY_SCOPE_AGENT)) < 0) {}
    }
    for (int o = 1; o < 64; o <<= 1) v += __shfl_xor(v, o);
    if (t == 0) boffs = v;
  }
  __syncthreads();
  int run = boffs + sd[t] - ts;
#pragma unroll
  for (int i = 0; i < SCAN_ITEMS; i++) {
    int idx = base + i;
    if (idx < N_NODES) row_ptr[idx] = run;
    run += vals[i];
  }
  if (b == 0 && t == 0) row_ptr[N_NODES] = E_TOT;
}

__global__ __launch_bounds__(256) void k_scatter(const int* __restrict__ ei,
                                                 const int* __restrict__ row_ptr,
                                                 const unsigned short* __restrict__ epos,
                                                 int* __restrict__ colA) {
  int tid = blockIdx.x * 256 + threadIdx.x;
  if (tid >= E_TOT) return;
  int s, d;
  if (tid < E_EDGES) { s = ei[tid]; d = ei[E_EDGES + tid]; }
  else { s = tid - E_EDGES; d = s; }
  colA[row_ptr[d] + (int)epos[tid]] = s;
}

// ---------------- Layer-1 aggregation + in-wave CSR sort + fused layer-2 transform ----------------
// r10 champion form exactly (plain w2t[132], half-split epilogue = measured 128.1 us).
__global__ __launch_bounds__(256) void k_agg1(const unsigned short* __restrict__ Hlb,
                                              const unsigned short* __restrict__ Hrb,
                                              const int* __restrict__ row_ptr, int* __restrict__ colA,
                                              const float* __restrict__ att, const float* __restrict__ bias,
                                              const float* __restrict__ W2l, const float* __restrict__ W2r,
                                              float* __restrict__ yl, float* __restrict__ yr) {
  __shared__ float hsh[4][FDIM];
  __shared__ int sidx[4][64];
  __shared__ float w2t[2][C2][132];   // transposed W2, +4 pad
  for (int i = threadIdx.x; i < FDIM * C2; i += 256) {
    int k = i / C2, cc = i - C2 * k;
    w2t[0][cc][k] = W2l[i];
    w2t[1][cc][k] = W2r[i];
  }
  __syncthreads();

  int w = threadIdx.x >> 6;
  int node = blockIdx.x * 4 + w;
  int lane = threadIdx.x & 63;
  int c0 = 2 * lane;
  const unsigned int* Hl32 = (const unsigned int*)Hlb;   // row = 64 uints
  const unsigned int* Hr32 = (const unsigned int*)Hrb;
  f32x2 xr = up2v(Hr32[((size_t)node << 6) + lane]);
  f32x2 av; av.x = att[c0] * LOG2E; av.y = att[c0 + 1] * LOG2E;
  int beg = row_ptr[node], end = row_ptr[node + 1];
  int deg = end - beg;
  bool small = deg <= 64;

  if (small) {
    // in-wave bitonic sort (canonical ascending order -> deterministic FP order)
    int v = (lane < deg) ? colA[beg + lane] : 0x7FFFFFFF;
#pragma unroll
    for (int k = 2; k <= 64; k <<= 1) {
#pragma unroll
      for (int j = k >> 1; j > 0; j >>= 1) {
        int other = __shfl_xor(v, j);
        bool up = ((lane & k) == 0);
        bool lower = ((lane & j) == 0);
        int mn = min(v, other), mx = max(v, other);
        v = (lower == up) ? mn : mx;
      }
    }
    sidx[w][lane] = v;                      // intra-wave: DS ops in order
    if (lane < deg) colA[beg + lane] = v;   // sorted row for agg2
  } else {
    if (lane == 0) {
      for (int i = beg + 1; i < end; i++) {
        int vv = colA[i];
        int j = i - 1;
        while (j >= beg && colA[j] > vv) { colA[j + 1] = colA[j]; j--; }
        colA[j + 1] = vv;
      }
    }
    __threadfence_block();
  }

  float l = 0.f;
  f32x2 acc = {0.f, 0.f};
  auto update = [&](unsigned int vv) {
    f32x2 xl = up2v(vv);
    f32x2 t = xl + xr;                       // v_pk_add_f32
    f32x2 u = t * NEG;                       // v_pk_mul_f32
    t = __builtin_elementwise_max(t, u);     // v_pk_max_f32: leaky = max(t, 0.2t)
    f32x2 m = t * av;                        // v_pk_mul_f32
    float p = row16_sum(m.x + m.y);
    float ww = __builtin_amdgcn_exp2f(fminf(p, PCLAMP));
    l += ww;
    acc += xl * ww;                          // v_pk_fma_f32
  };

  if (small) {
    const int* si = sidx[w];
    int j = 0;
    for (; j + 8 <= deg; j += 8) {
      unsigned int v0 = Hl32[((size_t)si[j + 0] << 6) + lane];
      unsigned int v1 = Hl32[((size_t)si[j + 1] << 6) + lane];
      unsigned int v2 = Hl32[((size_t)si[j + 2] << 6) + lane];
      unsigned int v3 = Hl32[((size_t)si[j + 3] << 6) + lane];
      unsigned int v4 = Hl32[((size_t)si[j + 4] << 6) + lane];
      unsigned int v5 = Hl32[((size_t)si[j + 5] << 6) + lane];
      unsigned int v6 = Hl32[((size_t)si[j + 6] << 6) + lane];
      unsigned int v7 = Hl32[((size_t)si[j + 7] << 6) + lane];
      update(v0); update(v1); update(v2); update(v3);
      update(v4); update(v5); update(v6); update(v7);
    }
    for (; j + 2 <= deg; j += 2) {
      unsigned int v0 = Hl32[((size_t)si[j + 0] << 6) + lane];
      unsigned int v1 = Hl32[((size_t)si[j + 1] << 6) + lane];
      update(v0); update(v1);
    }
    if (j < deg) update(Hl32[((size_t)si[j] << 6) + lane]);
  } else {
    for (int j = beg; j < end; j++) update(Hl32[((size_t)colA[j] << 6) + lane]);
  }

  float inv = 1.f / l;
  float ox = fmaxf(fmaf(acc.x, inv, bias[c0]),     0.f);   // fused ReLU
  float oy = fmaxf(fmaf(acc.y, inv, bias[c0 + 1]), 0.f);
  hsh[w][c0] = ox; hsh[w][c0 + 1] = oy;
  // epilogue: 2 lanes per output (lane 2o: k4 0..15, lane 2o+1: k4 16..31), shfl combine
  if (lane < 4 * C2) {
    int o = lane >> 1;               // output 0..19
    int half = lane & 1;             // k-range half
    bool isl = o < C2;
    int cc = isl ? o : o - C2;
    const float4* wrow = (const float4*)&w2t[isl ? 0 : 1][cc][0];
    const float4* h4 = (const float4*)hsh[w];
    float a2 = 0.f;
    int k0 = half << 4;
#pragma unroll
    for (int k4 = 0; k4 < 16; k4++) {
      float4 hv = h4[k0 + k4];
      float4 wv = wrow[k0 + k4];
      a2 = fmaf(hv.x, wv.x, a2);
      a2 = fmaf(hv.y, wv.y, a2);
      a2 = fmaf(hv.z, wv.z, a2);
      a2 = fmaf(hv.w, wv.w, a2);
    }
    a2 += __shfl_xor(a2, 1);         // fixed tree: (low half)+(high half)
    if (half == 0) {
      float* Y = isl ? yl : yr;
      Y[(size_t)node * YPAD + cc] = a2;
    }
  }
}

// ---------------- Layer-2 aggregation: 1 wave/node, 8-way edge-parallel, 2 ch/lane packed ----------------
__global__ __launch_bounds__(256) void k_agg2(const float* __restrict__ yl, const float* __restrict__ yr,
                                              const int* __restrict__ row_ptr, const int* __restrict__ colA,
                                              const float* __restrict__ att, const float* __restrict__ bias,
                                              float* __restrict__ outp) {
  int w = threadIdx.x >> 6;
  int node = blockIdx.x * 4 + w;
  if (node >= N_NODES) return;
  int lane = threadIdx.x & 63;
  int ch = 2 * (lane & 7);     // channel pair this lane owns
  int g  = lane >> 3;          // edge-group 0..7
  bool act = ch < C2;
  f32x2 xr = {0.f, 0.f};
  f32x2 a2 = {0.f, 0.f};
  if (act) {
    const float2* yr2 = (const float2*)(yr + (size_t)node * YPAD);
    float2 t = yr2[lane & 7];
    xr.x = t.x; xr.y = t.y;
    a2.x = att[ch] * LOG2E; a2.y = att[ch + 1] * LOG2E;
  }
  int beg = row_ptr[node], end = row_ptr[node + 1];
  float l = 0.f;
  f32x2 acc = {0.f, 0.f};
  const float2* ylL = (const float2*)yl + (lane & 7);   // row s at (s<<3) float2 units

  auto update = [&](f32x2 xl) {
    f32x2 t = xl + xr;                       // v_pk_add_f32
    f32x2 u = t * NEG;                       // v_pk_mul_f32
    t = __builtin_elementwise_max(t, u);     // v_pk_max_f32
    f32x2 m = t * a2;                        // v_pk_mul_f32
    float p = row8_sum(m.x + m.y);           // 8-lane group reduce (inactive lanes add 0)
    float wgt = __builtin_amdgcn_exp2f(fminf(p, PCLAMP));
    l += wgt;
    acc += xl * wgt;                         // v_pk_fma_f32
  };
  auto load = [&](int s) -> f32x2 {
    f32x2 r = {0.f, 0.f};
    if (act) {
      float2 t = ylL[(size_t)s << 3];        // yl row stride 16 floats = 8 float2
      r.x = t.x; r.y = t.y;
    }
    return r;
  };

  int j = beg + g;
  for (; j + 8 < end; j += 16) {             // 2 edges of this group: j, j+8
    int s0 = colA[j], s1 = colA[j + 8];
    f32x2 x0 = load(s0), x1 = load(s1);
    update(x0); update(x1);
  }
  if (j < end) update(load(colA[j]));

  // fixed combine tree across the 8 groups (deterministic)
  for (int o = 8; o <= 32; o <<= 1) {
    l     += __shfl_xor(l, o);
    acc.x += __shfl_xor(acc.x, o);
    acc.y += __shfl_xor(acc.y, o);
  }
  if (g == 0 && act) {
    float2 o;
    o.x = acc.x / l + bias[ch];
    o.y = acc.y / l + bias[ch + 1];
    *(float2*)(outp + (size_t)node * C2 + ch) = o;
  }
}

extern "C" void kernel_launch(void* const* d_in, const int* in_sizes, int n_in,
                              void* d_out, int out_size, void* d_ws, size_t ws_size,
                              hipStream_t stream) {
  const float* x    = (const float*)d_in[0];
  const int*   ei   = (const int*)d_in[1];
  const float* W1l  = (const float*)d_in[2];
  const float* W1r  = (const float*)d_in[3];
  const float* att1 = (const float*)d_in[4];
  const float* b1   = (const float*)d_in[5];
  const float* W2l  = (const float*)d_in[6];
  const float* W2r  = (const float*)d_in[7];
  const float* att2 = (const float*)d_in[8];
  const float* b2   = (const float*)d_in[9];
  float* out = (float*)d_out;

  char* ws = (char*)d_ws;
  size_t off = 0;
  auto take = [&](size_t bytes) -> char* {
    char* p = ws + off;
    off = (off + bytes + 511) & ~(size_t)511;
    return p;
  };
  unsigned short* Hlb = (unsigned short*)take((size_t)N_NODES * FDIM * sizeof(unsigned short)); // 25.6 MB
  unsigned short* Hrb = (unsigned short*)take((size_t)N_NODES * FDIM * sizeof(unsigned short)); // 25.6 MB
  unsigned short* Wt  = (unsigned short*)take((size_t)256 * 128 * sizeof(unsigned short));      // 64 KB
  float* yl      = (float*)take((size_t)N_NODES * YPAD * sizeof(float));   // 6.4 MB
  float* yr      = (float*)take((size_t)N_NODES * YPAD * sizeof(float));   // 6.4 MB
  int*   cnt     = (int*)take((size_t)N_NODES * sizeof(int));
  int*   row_ptr = (int*)take((size_t)(N_NODES + 1) * sizeof(int));
  int*   colA    = (int*)take((size_t)E_TOT * sizeof(int));
  unsigned short* epos = (unsigned short*)take((size_t)E_TOT * sizeof(unsigned short));  // 3.4 MB
  int*   agg     = (int*)take(256);
  if (off > ws_size) return;

  k_prep_w <<<NWT, 256, 0, stream>>>(W1l, W1r, Wt, cnt, agg);
  k_gc     <<<GB4 + NDEG, 256, 0, stream>>>(x, Wt, Hlb, Hrb, ei, cnt, epos);
  k_scan   <<<SCAN_NBLK, 256, 0, stream>>>(cnt, row_ptr, agg);
  k_scatter<<<(E_TOT + 255) / 256, 256, 0, stream>>>(ei, row_ptr, epos, colA);
  k_agg1   <<<(N_NODES + 3) / 4, 256, 0, stream>>>(Hlb, Hrb, row_ptr, colA, att1, b1, W2l, W2r, yl, yr);
  k_agg2   <<<(N_NODES + 3) / 4, 256, 0, stream>>>(yl, yr, row_ptr, colA, att2, b2, out);
}

// Round 15
// 395.568 us; speedup vs baseline: 1.3486x; 1.0228x over previous
//
#include <hip/hip_runtime.h>

#define N_NODES 100000
#define E_EDGES 1600000
#define E_TOT   1700000   // edges + self loops
#define FDIM    128       // F_IN and HEADS*HID
#define C2      10        // classes
#define YPAD    16        // yl/yr row stride (one 64B line)
#define NEG     0.2f
#define LOG2E   1.44269504088896f
#define PCLAMP  80.0f

#define NDEG    ((E_TOT + 255) / 256)        // 6641 edge chunks
#define NWT     128                          // 32768 / 256
#define GB4     ((N_NODES + 255) / 256)      // 391 gemm blocks (64 rows/wave)

typedef __attribute__((ext_vector_type(8))) short short8;
typedef __attribute__((ext_vector_type(4))) float f32x4;
typedef __attribute__((ext_vector_type(2))) float f32x2;

// 16-lane / 8-lane row reductions via DPP (pure VALU, no LDS pipe)
template <int CTRL>
__device__ __forceinline__ float dpp_add(float x) {
  return x + __int_as_float(
      __builtin_amdgcn_update_dpp(0, __float_as_int(x), CTRL, 0xF, 0xF, true));
}
__device__ __forceinline__ float row16_sum(float p) {
  p = dpp_add<0xB1>(p);
  p = dpp_add<0x4E>(p);
  p = dpp_add<0x141>(p);
  p = dpp_add<0x140>(p);
  return p;
}
__device__ __forceinline__ float row8_sum(float p) {
  p = dpp_add<0xB1>(p);
  p = dpp_add<0x4E>(p);
  p = dpp_add<0x141>(p);
  return p;
}

// fp32 -> bf16 (round-nearest-even), and packed bf16x2 -> float2
__device__ __forceinline__ unsigned short f2bf(float f) {
  unsigned int u = __float_as_uint(f);
  u += 0x7FFFu + ((u >> 16) & 1u);
  return (unsigned short)(u >> 16);
}
__device__ __forceinline__ f32x2 up2v(unsigned int v) {
  f32x2 r;
  r.x = __uint_as_float(v << 16);
  r.y = __uint_as_float(v & 0xFFFF0000u);
  return r;
}

// adaptive-depth in-wave bitonic sort: lanes >= deg hold INT_MAX; stopping at KMAX
// leaves blocks of KMAX sorted alternately asc/desc, but all desc blocks are constant
// INT_MAX (deg <= KMAX) -> globally ascending. Same final order as full sort.
template <int KMAX>
__device__ __forceinline__ int bsort(int v, int lane) {
#pragma unroll
  for (int k = 2; k <= KMAX; k <<= 1) {
#pragma unroll
    for (int j = k >> 1; j > 0; j >>= 1) {
      int other = __shfl_xor(v, j);
      bool up = ((lane & k) == 0);
      bool lower = ((lane & j) == 0);
      int mn = min(v, other), mx = max(v, other);
      v = (lower == up) ? mn : mx;
    }
  }
  return v;
}

#define SCAN_ITEMS 8
#define SCAN_CHUNK 2048
#define SCAN_NBLK  ((N_NODES + SCAN_CHUNK - 1) / SCAN_CHUNK)   // 49

// ---------------- W1 transpose + cnt zeroing + scan-lookback init ----------------
__global__ __launch_bounds__(256) void k_prep_w(const float* __restrict__ W1l, const float* __restrict__ W1r,
                                                unsigned short* __restrict__ Wt, int* __restrict__ cnt,
                                                int* __restrict__ agg) {
  int i = blockIdx.x * 256 + threadIdx.x;
  int n = i & 255, k = i >> 8;
  float v = (n < 128) ? W1l[k * 128 + n] : W1r[k * 128 + (n - 128)];
  Wt[n * 128 + k] = f2bf(v);   // B^T layout: row n, contiguous k
  for (int c = i; c < N_NODES; c += NWT * 256) cnt[c] = 0;
  if (blockIdx.x == 0 && threadIdx.x < SCAN_NBLK) agg[threadIdx.x] = -1;   // lookback sentinel
}

// ---------------- fused: Layer-1 GEMM (blocks < GB4) + degree count (rest) ----------------
// Register-blocked x4: one wave computes 64 rows; each B-fragment feeds 16 MFMA.
__global__ __launch_bounds__(256) void k_gc(const float* __restrict__ x,
                                            const unsigned short* __restrict__ Wt,
                                            unsigned short* __restrict__ Hlb,
                                            unsigned short* __restrict__ Hrb,
                                            const int* __restrict__ ei, int* __restrict__ cnt,
                                            unsigned short* __restrict__ epos) {
  int b = blockIdx.x;
  if (b >= GB4) {
    int tid = (b - GB4) * 256 + threadIdx.x;
    if (tid < E_TOT) {
      int d = (tid < E_EDGES) ? ei[E_EDGES + tid] : (tid - E_EDGES);
      epos[tid] = (unsigned short)atomicAdd(&cnt[d], 1);
    }
    return;
  }
  int w = threadIdx.x >> 6, lane = threadIdx.x & 63;
  int m = lane & 15, quad = lane >> 4;
  int wrow0 = b * 256 + w * 64;
  short8 A[4][4];   // [row-group][k-chunk]
#pragma unroll
  for (int g = 0; g < 4; g++) {
    int arow = wrow0 + g * 16 + m;
    bool aok = arow < N_NODES;
    const float4* ap = (const float4*)(x + (size_t)arow * FDIM + quad * 8);
#pragma unroll
    for (int c = 0; c < 4; c++) {
      short8 a = {};
      if (aok) {
        float4 v0 = ap[c * 8 + 0];
        float4 v1 = ap[c * 8 + 1];
        a[0] = (short)f2bf(v0.x); a[1] = (short)f2bf(v0.y);
        a[2] = (short)f2bf(v0.z); a[3] = (short)f2bf(v0.w);
        a[4] = (short)f2bf(v1.x); a[5] = (short)f2bf(v1.y);
        a[6] = (short)f2bf(v1.z); a[7] = (short)f2bf(v1.w);
      }
      A[g][c] = a;
    }
  }

#pragma unroll
  for (int t0 = 0; t0 < 16; t0++) {
    const short8* bp = (const short8*)(Wt + (size_t)(t0 * 16 + m) * 128 + quad * 8);
    short8 B0 = bp[0], B1 = bp[4], B2 = bp[8], B3 = bp[12];
    int n0 = t0 * 16;
    unsigned short* dst = (n0 < 128) ? Hlb : Hrb;
    int col = (n0 < 128) ? n0 + m : (n0 - 128) + m;
#pragma unroll
    for (int g = 0; g < 4; g++) {
      f32x4 acc = {0.f, 0.f, 0.f, 0.f};
      acc = __builtin_amdgcn_mfma_f32_16x16x32_bf16(A[g][0], B0, acc, 0, 0, 0);
      acc = __builtin_amdgcn_mfma_f32_16x16x32_bf16(A[g][1], B1, acc, 0, 0, 0);
      acc = __builtin_amdgcn_mfma_f32_16x16x32_bf16(A[g][2], B2, acc, 0, 0, 0);
      acc = __builtin_amdgcn_mfma_f32_16x16x32_bf16(A[g][3], B3, acc, 0, 0, 0);
      int orow = wrow0 + g * 16 + quad * 4;
#pragma unroll
      for (int r = 0; r < 4; r++) {
        int row = orow + r;
        if (row < N_NODES) dst[(size_t)row * FDIM + col] = f2bf(acc[r]);
      }
    }
  }
}

// ---------------- fused scan: per-chunk scan + decoupled lookback (49 blocks only) ----------------
__global__ __launch_bounds__(256) void k_scan(const int* __restrict__ cnt, int* __restrict__ row_ptr,
                                              int* __restrict__ agg) {
  int b = blockIdx.x, t = threadIdx.x;
  int base = b * SCAN_CHUNK + t * SCAN_ITEMS;
  int vals[SCAN_ITEMS]; int ts = 0;
#pragma unroll
  for (int i = 0; i < SCAN_ITEMS; i++) {
    int idx = base + i;
    vals[i] = (idx < N_NODES) ? cnt[idx] : 0;
    ts += vals[i];
  }
  __shared__ int sd[256];
  sd[t] = ts; __syncthreads();
  for (int o = 1; o < 256; o <<= 1) {
    int v = 0;
    if (t >= o) v = sd[t - o];
    __syncthreads();
    sd[t] += v;
    __syncthreads();
  }
  if (t == 0)
    __hip_atomic_store(&agg[b], sd[255], __ATOMIC_RELEASE, __HIP_MEMORY_SCOPE_AGENT);
  __shared__ int boffs;
  if (t < 64) {
    int v = 0;
    if (t < b) {   // b <= 48 < 64: one wave covers the full prefix
      while ((v = __hip_atomic_load(&agg[t], __ATOMIC_ACQUIRE, __HIP_MEMORY_SCOPE_AGENT)) < 0) {}
    }
    for (int o = 1; o < 64; o <<= 1) v += __shfl_xor(v, o);
    if (t == 0) boffs = v;
  }
  __syncthreads();
  int run = boffs + sd[t] - ts;
#pragma unroll
  for (int i = 0; i < SCAN_ITEMS; i++) {
    int idx = base + i;
    if (idx < N_NODES) row_ptr[idx] = run;
    run += vals[i];
  }
  if (b == 0 && t == 0) row_ptr[N_NODES] = E_TOT;
}

__global__ __launch_bounds__(256) void k_scatter(const int* __restrict__ ei,
                                                 const int* __restrict__ row_ptr,
                                                 const unsigned short* __restrict__ epos,
                                                 int* __restrict__ colA) {
  int tid = blockIdx.x * 256 + threadIdx.x;
  if (tid >= E_TOT) return;
  int s, d;
  if (tid < E_EDGES) { s = ei[tid]; d = ei[E_EDGES + tid]; }
  else { s = tid - E_EDGES; d = s; }
  colA[row_ptr[d] + (int)epos[tid]] = s;
}

// ---------------- Layer-1 aggregation + in-wave CSR sort + fused layer-2 transform ----------------
// r10 champion structure; this round: adaptive-depth sort (kmax from deg bucket).
__global__ __launch_bounds__(256) void k_agg1(const unsigned short* __restrict__ Hlb,
                                              const unsigned short* __restrict__ Hrb,
                                              const int* __restrict__ row_ptr, int* __restrict__ colA,
                                              const float* __restrict__ att, const float* __restrict__ bias,
                                              const float* __restrict__ W2l, const float* __restrict__ W2r,
                                              float* __restrict__ yl, float* __restrict__ yr) {
  __shared__ float hsh[4][FDIM];
  __shared__ int sidx[4][64];
  __shared__ float w2t[2][C2][132];   // transposed W2, +4 pad
  for (int i = threadIdx.x; i < FDIM * C2; i += 256) {
    int k = i / C2, cc = i - C2 * k;
    w2t[0][cc][k] = W2l[i];
    w2t[1][cc][k] = W2r[i];
  }
  __syncthreads();

  int w = threadIdx.x >> 6;
  int node = blockIdx.x * 4 + w;
  int lane = threadIdx.x & 63;
  int c0 = 2 * lane;
  const unsigned int* Hl32 = (const unsigned int*)Hlb;   // row = 64 uints
  const unsigned int* Hr32 = (const unsigned int*)Hrb;
  f32x2 xr = up2v(Hr32[((size_t)node << 6) + lane]);
  f32x2 av; av.x = att[c0] * LOG2E; av.y = att[c0 + 1] * LOG2E;
  int beg = row_ptr[node], end = row_ptr[node + 1];
  int deg = end - beg;
  bool small = deg <= 64;

  if (small) {
    int v = (lane < deg) ? colA[beg + lane] : 0x7FFFFFFF;
    if (deg <= 16)      v = bsort<16>(v, lane);   // ~46% of nodes: 10 stages
    else if (deg <= 32) v = bsort<32>(v, lane);   // ~54%: 15 stages
    else                v = bsort<64>(v, lane);   // rare: full 21 stages
    sidx[w][lane] = v;                      // intra-wave: DS ops in order
    if (lane < deg) colA[beg + lane] = v;   // sorted row for agg2
  } else {
    if (lane == 0) {
      for (int i = beg + 1; i < end; i++) {
        int vv = colA[i];
        int j = i - 1;
        while (j >= beg && colA[j] > vv) { colA[j + 1] = colA[j]; j--; }
        colA[j + 1] = vv;
      }
    }
    __threadfence_block();
  }

  float l = 0.f;
  f32x2 acc = {0.f, 0.f};
  auto update = [&](unsigned int vv) {
    f32x2 xl = up2v(vv);
    f32x2 t = xl + xr;                       // v_pk_add_f32
    f32x2 u = t * NEG;                       // v_pk_mul_f32
    t = __builtin_elementwise_max(t, u);     // v_pk_max_f32: leaky = max(t, 0.2t)
    f32x2 m = t * av;                        // v_pk_mul_f32
    float p = row16_sum(m.x + m.y);
    float ww = __builtin_amdgcn_exp2f(fminf(p, PCLAMP));
    l += ww;
    acc += xl * ww;                          // v_pk_fma_f32
  };

  if (small) {
    const int* si = sidx[w];
    int j = 0;
    for (; j + 8 <= deg; j += 8) {
      unsigned int v0 = Hl32[((size_t)si[j + 0] << 6) + lane];
      unsigned int v1 = Hl32[((size_t)si[j + 1] << 6) + lane];
      unsigned int v2 = Hl32[((size_t)si[j + 2] << 6) + lane];
      unsigned int v3 = Hl32[((size_t)si[j + 3] << 6) + lane];
      unsigned int v4 = Hl32[((size_t)si[j + 4] << 6) + lane];
      unsigned int v5 = Hl32[((size_t)si[j + 5] << 6) + lane];
      unsigned int v6 = Hl32[((size_t)si[j + 6] << 6) + lane];
      unsigned int v7 = Hl32[((size_t)si[j + 7] << 6) + lane];
      update(v0); update(v1); update(v2); update(v3);
      update(v4); update(v5); update(v6); update(v7);
    }
    for (; j + 2 <= deg; j += 2) {
      unsigned int v0 = Hl32[((size_t)si[j + 0] << 6) + lane];
      unsigned int v1 = Hl32[((size_t)si[j + 1] << 6) + lane];
      update(v0); update(v1);
    }
    if (j < deg) update(Hl32[((size_t)si[j] << 6) + lane]);
  } else {
    for (int j = beg; j < end; j++) update(Hl32[((size_t)colA[j] << 6) + lane]);
  }

  float inv = 1.f / l;
  float ox = fmaxf(fmaf(acc.x, inv, bias[c0]),     0.f);   // fused ReLU
  float oy = fmaxf(fmaf(acc.y, inv, bias[c0 + 1]), 0.f);
  hsh[w][c0] = ox; hsh[w][c0 + 1] = oy;
  // epilogue: 2 lanes per output (lane 2o: k4 0..15, lane 2o+1: k4 16..31), shfl combine
  if (lane < 4 * C2) {
    int o = lane >> 1;               // output 0..19
    int half = lane & 1;             // k-range half
    bool isl = o < C2;
    int cc = isl ? o : o - C2;
    const float4* wrow = (const float4*)&w2t[isl ? 0 : 1][cc][0];
    const float4* h4 = (const float4*)hsh[w];
    float a2 = 0.f;
    int k0 = half << 4;
#pragma unroll
    for (int k4 = 0; k4 < 16; k4++) {
      float4 hv = h4[k0 + k4];
      float4 wv = wrow[k0 + k4];
      a2 = fmaf(hv.x, wv.x, a2);
      a2 = fmaf(hv.y, wv.y, a2);
      a2 = fmaf(hv.z, wv.z, a2);
      a2 = fmaf(hv.w, wv.w, a2);
    }
    a2 += __shfl_xor(a2, 1);         // fixed tree: (low half)+(high half)
    if (half == 0) {
      float* Y = isl ? yl : yr;
      Y[(size_t)node * YPAD + cc] = a2;
    }
  }
}

// ---------------- Layer-2 aggregation: 1 wave/node, 8-way edge-parallel, 2 ch/lane packed ----------------
__global__ __launch_bounds__(256) void k_agg2(const float* __restrict__ yl, const float* __restrict__ yr,
                                              const int* __restrict__ row_ptr, const int* __restrict__ colA,
                                              const float* __restrict__ att, const float* __restrict__ bias,
                                              float* __restrict__ outp) {
  int w = threadIdx.x >> 6;
  int node = blockIdx.x * 4 + w;
  if (node >= N_NODES) return;
  int lane = threadIdx.x & 63;
  int ch = 2 * (lane & 7);     // channel pair this lane owns
  int g  = lane >> 3;          // edge-group 0..7
  bool act = ch < C2;
  f32x2 xr = {0.f, 0.f};
  f32x2 a2 = {0.f, 0.f};
  if (act) {
    const float2* yr2 = (const float2*)(yr + (size_t)node * YPAD);
    float2 t = yr2[lane & 7];
    xr.x = t.x; xr.y = t.y;
    a2.x = att[ch] * LOG2E; a2.y = att[ch + 1] * LOG2E;
  }
  int beg = row_ptr[node], end = row_ptr[node + 1];
  float l = 0.f;
  f32x2 acc = {0.f, 0.f};
  const float2* ylL = (const float2*)yl + (lane & 7);   // row s at (s<<3) float2 units

  auto update = [&](f32x2 xl) {
    f32x2 t = xl + xr;                       // v_pk_add_f32
    f32x2 u = t * NEG;                       // v_pk_mul_f32
    t = __builtin_elementwise_max(t, u);     // v_pk_max_f32
    f32x2 m = t * a2;                        // v_pk_mul_f32
    float p = row8_sum(m.x + m.y);           // 8-lane group reduce (inactive lanes add 0)
    float wgt = __builtin_amdgcn_exp2f(fminf(p, PCLAMP));
    l += wgt;
    acc += xl * wgt;                         // v_pk_fma_f32
  };
  auto load = [&](int s) -> f32x2 {
    f32x2 r = {0.f, 0.f};
    if (act) {
      float2 t = ylL[(size_t)s << 3];        // yl row stride 16 floats = 8 float2
      r.x = t.x; r.y = t.y;
    }
    return r;
  };

  int j = beg + g;
  for (; j + 8 < end; j += 16) {             // 2 edges of this group: j, j+8
    int s0 = colA[j], s1 = colA[j + 8];
    f32x2 x0 = load(s0), x1 = load(s1);
    update(x0); update(x1);
  }
  if (j < end) update(load(colA[j]));

  // fixed combine tree across the 8 groups (deterministic)
  for (int o = 8; o <= 32; o <<= 1) {
    l     += __shfl_xor(l, o);
    acc.x += __shfl_xor(acc.x, o);
    acc.y += __shfl_xor(acc.y, o);
  }
  if (g == 0 && act) {
    float2 o;
    o.x = acc.x / l + bias[ch];
    o.y = acc.y / l + bias[ch + 1];
    *(float2*)(outp + (size_t)node * C2 + ch) = o;
  }
}

extern "C" void kernel_launch(void* const* d_in, const int* in_sizes, int n_in,
                              void* d_out, int out_size, void* d_ws, size_t ws_size,
                              hipStream_t stream) {
  const float* x    = (const float*)d_in[0];
  const int*   ei   = (const int*)d_in[1];
  const float* W1l  = (const float*)d_in[2];
  const float* W1r  = (const float*)d_in[3];
  const float* att1 = (const float*)d_in[4];
  const float* b1   = (const float*)d_in[5];
  const float* W2l  = (const float*)d_in[6];
  const float* W2r  = (const float*)d_in[7];
  const float* att2 = (const float*)d_in[8];
  const float* b2   = (const float*)d_in[9];
  float* out = (float*)d_out;

  char* ws = (char*)d_ws;
  size_t off = 0;
  auto take = [&](size_t bytes) -> char* {
    char* p = ws + off;
    off = (off + bytes + 511) & ~(size_t)511;
    return p;
  };
  unsigned short* Hlb = (unsigned short*)take((size_t)N_NODES * FDIM * sizeof(unsigned short)); // 25.6 MB
  unsigned short* Hrb = (unsigned short*)take((size_t)N_NODES * FDIM * sizeof(unsigned short)); // 25.6 MB
  unsigned short* Wt  = (unsigned short*)take((size_t)256 * 128 * sizeof(unsigned short));      // 64 KB
  float* yl      = (float*)take((size_t)N_NODES * YPAD * sizeof(float));   // 6.4 MB
  float* yr      = (float*)take((size_t)N_NODES * YPAD * sizeof(float));   // 6.4 MB
  int*   cnt     = (int*)take((size_t)N_NODES * sizeof(int));
  int*   row_ptr = (int*)take((size_t)(N_NODES + 1) * sizeof(int));
  int*   colA    = (int*)take((size_t)E_TOT * sizeof(int));
  unsigned short* epos = (unsigned short*)take((size_t)E_TOT * sizeof(unsigned short));  // 3.4 MB
  int*   agg     = (int*)take(256);
  if (off > ws_size) return;

  k_prep_w <<<NWT, 256, 0, stream>>>(W1l, W1r, Wt, cnt, agg);
  k_gc     <<<GB4 + NDEG, 256, 0, stream>>>(x, Wt, Hlb, Hrb, ei, cnt, epos);
  k_scan   <<<SCAN_NBLK, 256, 0, stream>>>(cnt, row_ptr, agg);
  k_scatter<<<(E_TOT + 255) / 256, 256, 0, stream>>>(ei, row_ptr, epos, colA);
  k_agg1   <<<(N_NODES + 3) / 4, 256, 0, stream>>>(Hlb, Hrb, row_ptr, colA, att1, b1, W2l, W2r, yl, yr);
  k_agg2   <<<(N_NODES + 3) / 4, 256, 0, stream>>>(yl, yr, row_ptr, colA, att2, b2, out);
}

// Round 16
// 345.429 us; speedup vs baseline: 1.5444x; 1.1451x over previous
//
#include <hip/hip_runtime.h>

#define N_NODES 100000
#define E_EDGES 1600000
#define E_TOT   1700000   // edges + self loops
#define FDIM    128       // F_IN and HEADS*HID
#define C2      10        // classes
#define YPAD    16        // yl/yr row stride (one 64B line)
#define NEG     0.2f
#define LOG2E   1.44269504088896f
#define PCLAMP  80.0f

#define NWT     128                          // 32768 / 256
#define GB4     ((N_NODES + 255) / 256)      // 391 gemm blocks (64 rows/wave)
#define NBUK    98                           // dst>>10 buckets
#define BCAP    20480                        // per-bucket capacity (mean 17.4K + 23 sigma)
#define NBB     ((E_TOT + 2047) / 2048)      // 831 bucket-scatter blocks

typedef __attribute__((ext_vector_type(8))) short short8;
typedef __attribute__((ext_vector_type(4))) float f32x4;
typedef __attribute__((ext_vector_type(2))) float f32x2;

// 16-lane / 8-lane row reductions via DPP (pure VALU, no LDS pipe)
template <int CTRL>
__device__ __forceinline__ float dpp_add(float x) {
  return x + __int_as_float(
      __builtin_amdgcn_update_dpp(0, __float_as_int(x), CTRL, 0xF, 0xF, true));
}
__device__ __forceinline__ float row16_sum(float p) {
  p = dpp_add<0xB1>(p);
  p = dpp_add<0x4E>(p);
  p = dpp_add<0x141>(p);
  p = dpp_add<0x140>(p);
  return p;
}
__device__ __forceinline__ float row8_sum(float p) {
  p = dpp_add<0xB1>(p);
  p = dpp_add<0x4E>(p);
  p = dpp_add<0x141>(p);
  return p;
}

// fp32 -> bf16 (round-nearest-even), and packed bf16x2 -> float2
__device__ __forceinline__ unsigned short f2bf(float f) {
  unsigned int u = __float_as_uint(f);
  u += 0x7FFFu + ((u >> 16) & 1u);
  return (unsigned short)(u >> 16);
}
__device__ __forceinline__ f32x2 up2v(unsigned int v) {
  f32x2 r;
  r.x = __uint_as_float(v << 16);
  r.y = __uint_as_float(v & 0xFFFF0000u);
  return r;
}

// adaptive-depth in-wave bitonic sort (lanes >= deg hold INT_MAX)
template <int KMAX>
__device__ __forceinline__ int bsort(int v, int lane) {
#pragma unroll
  for (int k = 2; k <= KMAX; k <<= 1) {
#pragma unroll
    for (int j = k >> 1; j > 0; j >>= 1) {
      int other = __shfl_xor(v, j);
      bool up = ((lane & k) == 0);
      bool lower = ((lane & j) == 0);
      int mn = min(v, other), mx = max(v, other);
      v = (lower == up) ? mn : mx;
    }
  }
  return v;
}

// ---------------- W1 transpose + bucket-cursor zeroing ----------------
__global__ __launch_bounds__(256) void k_prep_w(const float* __restrict__ W1l, const float* __restrict__ W1r,
                                                unsigned short* __restrict__ Wt, int* __restrict__ bcur) {
  int i = blockIdx.x * 256 + threadIdx.x;
  int n = i & 255, k = i >> 8;
  float v = (n < 128) ? W1l[k * 128 + n] : W1r[k * 128 + (n - 128)];
  Wt[n * 128 + k] = f2bf(v);   // B^T layout: row n, contiguous k
  if (blockIdx.x == 0 && threadIdx.x < 128) bcur[threadIdx.x] = 0;
}

// ---------------- fused: Layer-1 GEMM (blocks < GB4) + coarse bucket-scatter (rest) ----------------
// Bucket-scatter: 2048-edge chunk -> LDS 98-bin histogram -> ONE global atomic per
// (block,bucket) reservation (81K total vs 1.7M per-edge) -> packed (lid<<17|src) writes.
__global__ __launch_bounds__(256) void k_gc(const float* __restrict__ x,
                                            const unsigned short* __restrict__ Wt,
                                            unsigned short* __restrict__ Hlb,
                                            unsigned short* __restrict__ Hrb,
                                            const int* __restrict__ ei, int* __restrict__ bcur,
                                            unsigned int* __restrict__ bkt) {
  __shared__ int lhist[NBUK], lbase[NBUK];
  int b = blockIdx.x;
  if (b >= GB4) {
    int t = threadIdx.x;
    int e0 = (b - GB4) * 2048;
    int e1 = min(e0 + 2048, E_TOT);
    if (t < NBUK) lhist[t] = 0;
    __syncthreads();
    for (int e = e0 + t; e < e1; e += 256) {
      int d = (e < E_EDGES) ? ei[E_EDGES + e] : (e - E_EDGES);
      atomicAdd(&lhist[d >> 10], 1);
    }
    __syncthreads();
    if (t < NBUK) { lbase[t] = atomicAdd(&bcur[t], lhist[t]); lhist[t] = 0; }
    __syncthreads();
    for (int e = e0 + t; e < e1; e += 256) {
      int s, d;
      if (e < E_EDGES) { s = ei[e]; d = ei[E_EDGES + e]; }
      else { s = e - E_EDGES; d = s; }
      int lb = d >> 10;
      int pos = lbase[lb] + atomicAdd(&lhist[lb], 1);
      bkt[(size_t)lb * BCAP + pos] = ((unsigned)(d & 1023) << 17) | (unsigned)s;
    }
    return;
  }
  int w = threadIdx.x >> 6, lane = threadIdx.x & 63;
  int m = lane & 15, quad = lane >> 4;
  int wrow0 = b * 256 + w * 64;
  short8 A[4][4];   // [row-group][k-chunk]
#pragma unroll
  for (int g = 0; g < 4; g++) {
    int arow = wrow0 + g * 16 + m;
    bool aok = arow < N_NODES;
    const float4* ap = (const float4*)(x + (size_t)arow * FDIM + quad * 8);
#pragma unroll
    for (int c = 0; c < 4; c++) {
      short8 a = {};
      if (aok) {
        float4 v0 = ap[c * 8 + 0];
        float4 v1 = ap[c * 8 + 1];
        a[0] = (short)f2bf(v0.x); a[1] = (short)f2bf(v0.y);
        a[2] = (short)f2bf(v0.z); a[3] = (short)f2bf(v0.w);
        a[4] = (short)f2bf(v1.x); a[5] = (short)f2bf(v1.y);
        a[6] = (short)f2bf(v1.z); a[7] = (short)f2bf(v1.w);
      }
      A[g][c] = a;
    }
  }

#pragma unroll
  for (int t0 = 0; t0 < 16; t0++) {
    const short8* bp = (const short8*)(Wt + (size_t)(t0 * 16 + m) * 128 + quad * 8);
    short8 B0 = bp[0], B1 = bp[4], B2 = bp[8], B3 = bp[12];
    int n0 = t0 * 16;
    unsigned short* dst = (n0 < 128) ? Hlb : Hrb;
    int col = (n0 < 128) ? n0 + m : (n0 - 128) + m;
#pragma unroll
    for (int g = 0; g < 4; g++) {
      f32x4 acc = {0.f, 0.f, 0.f, 0.f};
      acc = __builtin_amdgcn_mfma_f32_16x16x32_bf16(A[g][0], B0, acc, 0, 0, 0);
      acc = __builtin_amdgcn_mfma_f32_16x16x32_bf16(A[g][1], B1, acc, 0, 0, 0);
      acc = __builtin_amdgcn_mfma_f32_16x16x32_bf16(A[g][2], B2, acc, 0, 0, 0);
      acc = __builtin_amdgcn_mfma_f32_16x16x32_bf16(A[g][3], B3, acc, 0, 0, 0);
      int orow = wrow0 + g * 16 + quad * 4;
#pragma unroll
      for (int r = 0; r < 4; r++) {
        int row = orow + r;
        if (row < N_NODES) dst[(size_t)row * FDIM + col] = f2bf(acc[r]);
      }
    }
  }
}

// ---------------- fine CSR build: one block per bucket (<=1024 nodes, ~17.4K edges) ----------------
// LDS 1024-bin histogram -> LDS scan -> row_ptr write -> LDS-cursor scatter into colA.
// No cross-block sync anywhere; bucket bases via redundant per-block scan of bcur.
__global__ __launch_bounds__(256) void k_bkt(const int* __restrict__ bcur,
                                             const unsigned int* __restrict__ bkt,
                                             int* __restrict__ row_ptr, int* __restrict__ colA) {
  __shared__ int eb[128];
  __shared__ int hist[1024];
  __shared__ int pfx[1024];
  __shared__ int sd[256];
  int b = blockIdx.x, t = threadIdx.x;
  // inclusive prefix over bucket sizes (redundant per block)
  if (t < 128) eb[t] = (t < NBUK) ? bcur[t] : 0;
  __syncthreads();
  for (int o = 1; o < 128; o <<= 1) {
    int v = 0;
    if (t < 128 && t >= o) v = eb[t - o];
    __syncthreads();
    if (t < 128) eb[t] += v;
    __syncthreads();
  }
  int ne = bcur[b];
  int base = eb[b] - ne;          // exclusive edge base of this bucket
  int node0 = b << 10;
  int nn = min(1024, N_NODES - node0);
#pragma unroll
  for (int i = 0; i < 4; i++) hist[t * 4 + i] = 0;
  __syncthreads();
  const unsigned int* mybkt = bkt + (size_t)b * BCAP;
  for (int e = t; e < ne; e += 256)
    atomicAdd(&hist[mybkt[e] >> 17], 1);
  __syncthreads();
  // scan 1024 bins (4 per thread + 256-wide Hillis-Steele)
  int b0 = 4 * t;
  int s0 = hist[b0], s1 = hist[b0 + 1], s2 = hist[b0 + 2], s3 = hist[b0 + 3];
  int ts = s0 + s1 + s2 + s3;
  sd[t] = ts; __syncthreads();
  for (int o = 1; o < 256; o <<= 1) {
    int v = 0;
    if (t >= o) v = sd[t - o];
    __syncthreads();
    sd[t] += v;
    __syncthreads();
  }
  int run = sd[t] - ts;           // exclusive partial
  pfx[b0] = run; pfx[b0 + 1] = run + s0; pfx[b0 + 2] = run + s0 + s1; pfx[b0 + 3] = run + s0 + s1 + s2;
  hist[b0] = 0; hist[b0 + 1] = 0; hist[b0 + 2] = 0; hist[b0 + 3] = 0;   // reuse as cursors
  __syncthreads();
  for (int i = t; i < nn; i += 256) row_ptr[node0 + i] = base + pfx[i];
  if (b == 0 && t == 0) row_ptr[N_NODES] = E_TOT;
  // scatter (order nondeterministic within row; agg1 sorts -> deterministic numerics)
  for (int e = t; e < ne; e += 256) {
    unsigned int u = mybkt[e];
    int lid = u >> 17;
    int pos = base + pfx[lid] + atomicAdd(&hist[lid], 1);
    colA[pos] = (int)(u & 0x1FFFFu);
  }
}

// ---------------- Layer-1 aggregation + in-wave CSR sort + fused layer-2 transform ----------------
// r15 champion: adaptive-depth sort + half-split epilogue (measured 125.4 us, 91-95% VALU).
__global__ __launch_bounds__(256) void k_agg1(const unsigned short* __restrict__ Hlb,
                                              const unsigned short* __restrict__ Hrb,
                                              const int* __restrict__ row_ptr, int* __restrict__ colA,
                                              const float* __restrict__ att, const float* __restrict__ bias,
                                              const float* __restrict__ W2l, const float* __restrict__ W2r,
                                              float* __restrict__ yl, float* __restrict__ yr) {
  __shared__ float hsh[4][FDIM];
  __shared__ int sidx[4][64];
  __shared__ float w2t[2][C2][132];   // transposed W2, +4 pad
  for (int i = threadIdx.x; i < FDIM * C2; i += 256) {
    int k = i / C2, cc = i - C2 * k;
    w2t[0][cc][k] = W2l[i];
    w2t[1][cc][k] = W2r[i];
  }
  __syncthreads();

  int w = threadIdx.x >> 6;
  int node = blockIdx.x * 4 + w;
  int lane = threadIdx.x & 63;
  int c0 = 2 * lane;
  const unsigned int* Hl32 = (const unsigned int*)Hlb;   // row = 64 uints
  const unsigned int* Hr32 = (const unsigned int*)Hrb;
  f32x2 xr = up2v(Hr32[((size_t)node << 6) + lane]);
  f32x2 av; av.x = att[c0] * LOG2E; av.y = att[c0 + 1] * LOG2E;
  int beg = row_ptr[node], end = row_ptr[node + 1];
  int deg = end - beg;
  bool small = deg <= 64;

  if (small) {
    int v = (lane < deg) ? colA[beg + lane] : 0x7FFFFFFF;
    if (deg <= 16)      v = bsort<16>(v, lane);
    else if (deg <= 32) v = bsort<32>(v, lane);
    else                v = bsort<64>(v, lane);
    sidx[w][lane] = v;                      // intra-wave: DS ops in order
    if (lane < deg) colA[beg + lane] = v;   // sorted row for agg2
  } else {
    if (lane == 0) {
      for (int i = beg + 1; i < end; i++) {
        int vv = colA[i];
        int j = i - 1;
        while (j >= beg && colA[j] > vv) { colA[j + 1] = colA[j]; j--; }
        colA[j + 1] = vv;
      }
    }
    __threadfence_block();
  }

  float l = 0.f;
  f32x2 acc = {0.f, 0.f};
  auto update = [&](unsigned int vv) {
    f32x2 xl = up2v(vv);
    f32x2 t = xl + xr;                       // v_pk_add_f32
    f32x2 u = t * NEG;                       // v_pk_mul_f32
    t = __builtin_elementwise_max(t, u);     // v_pk_max_f32: leaky = max(t, 0.2t)
    f32x2 m = t * av;                        // v_pk_mul_f32
    float p = row16_sum(m.x + m.y);
    float ww = __builtin_amdgcn_exp2f(fminf(p, PCLAMP));
    l += ww;
    acc += xl * ww;                          // v_pk_fma_f32
  };

  if (small) {
    const int* si = sidx[w];
    int j = 0;
    for (; j + 8 <= deg; j += 8) {
      unsigned int v0 = Hl32[((size_t)si[j + 0] << 6) + lane];
      unsigned int v1 = Hl32[((size_t)si[j + 1] << 6) + lane];
      unsigned int v2 = Hl32[((size_t)si[j + 2] << 6) + lane];
      unsigned int v3 = Hl32[((size_t)si[j + 3] << 6) + lane];
      unsigned int v4 = Hl32[((size_t)si[j + 4] << 6) + lane];
      unsigned int v5 = Hl32[((size_t)si[j + 5] << 6) + lane];
      unsigned int v6 = Hl32[((size_t)si[j + 6] << 6) + lane];
      unsigned int v7 = Hl32[((size_t)si[j + 7] << 6) + lane];
      update(v0); update(v1); update(v2); update(v3);
      update(v4); update(v5); update(v6); update(v7);
    }
    for (; j + 2 <= deg; j += 2) {
      unsigned int v0 = Hl32[((size_t)si[j + 0] << 6) + lane];
      unsigned int v1 = Hl32[((size_t)si[j + 1] << 6) + lane];
      update(v0); update(v1);
    }
    if (j < deg) update(Hl32[((size_t)si[j] << 6) + lane]);
  } else {
    for (int j = beg; j < end; j++) update(Hl32[((size_t)colA[j] << 6) + lane]);
  }

  float inv = 1.f / l;
  float ox = fmaxf(fmaf(acc.x, inv, bias[c0]),     0.f);   // fused ReLU
  float oy = fmaxf(fmaf(acc.y, inv, bias[c0 + 1]), 0.f);
  hsh[w][c0] = ox; hsh[w][c0 + 1] = oy;
  // epilogue: 2 lanes per output (lane 2o: k4 0..15, lane 2o+1: k4 16..31), shfl combine
  if (lane < 4 * C2) {
    int o = lane >> 1;               // output 0..19
    int half = lane & 1;             // k-range half
    bool isl = o < C2;
    int cc = isl ? o : o - C2;
    const float4* wrow = (const float4*)&w2t[isl ? 0 : 1][cc][0];
    const float4* h4 = (const float4*)hsh[w];
    float a2 = 0.f;
    int k0 = half << 4;
#pragma unroll
    for (int k4 = 0; k4 < 16; k4++) {
      float4 hv = h4[k0 + k4];
      float4 wv = wrow[k0 + k4];
      a2 = fmaf(hv.x, wv.x, a2);
      a2 = fmaf(hv.y, wv.y, a2);
      a2 = fmaf(hv.z, wv.z, a2);
      a2 = fmaf(hv.w, wv.w, a2);
    }
    a2 += __shfl_xor(a2, 1);         // fixed tree: (low half)+(high half)
    if (half == 0) {
      float* Y = isl ? yl : yr;
      Y[(size_t)node * YPAD + cc] = a2;
    }
  }
}

// ---------------- Layer-2 aggregation: 1 wave/node, 8-way edge-parallel, 2 ch/lane packed ----------------
__global__ __launch_bounds__(256) void k_agg2(const float* __restrict__ yl, const float* __restrict__ yr,
                                              const int* __restrict__ row_ptr, const int* __restrict__ colA,
                                              const float* __restrict__ att, const float* __restrict__ bias,
                                              float* __restrict__ outp) {
  int w = threadIdx.x >> 6;
  int node = blockIdx.x * 4 + w;
  if (node >= N_NODES) return;
  int lane = threadIdx.x & 63;
  int ch = 2 * (lane & 7);     // channel pair this lane owns
  int g  = lane >> 3;          // edge-group 0..7
  bool act = ch < C2;
  f32x2 xr = {0.f, 0.f};
  f32x2 a2 = {0.f, 0.f};
  if (act) {
    const float2* yr2 = (const float2*)(yr + (size_t)node * YPAD);
    float2 t = yr2[lane & 7];
    xr.x = t.x; xr.y = t.y;
    a2.x = att[ch] * LOG2E; a2.y = att[ch + 1] * LOG2E;
  }
  int beg = row_ptr[node], end = row_ptr[node + 1];
  float l = 0.f;
  f32x2 acc = {0.f, 0.f};
  const float2* ylL = (const float2*)yl + (lane & 7);   // row s at (s<<3) float2 units

  auto update = [&](f32x2 xl) {
    f32x2 t = xl + xr;                       // v_pk_add_f32
    f32x2 u = t * NEG;                       // v_pk_mul_f32
    t = __builtin_elementwise_max(t, u);     // v_pk_max_f32
    f32x2 m = t * a2;                        // v_pk_mul_f32
    float p = row8_sum(m.x + m.y);           // 8-lane group reduce (inactive lanes add 0)
    float wgt = __builtin_amdgcn_exp2f(fminf(p, PCLAMP));
    l += wgt;
    acc += xl * wgt;                         // v_pk_fma_f32
  };
  auto load = [&](int s) -> f32x2 {
    f32x2 r = {0.f, 0.f};
    if (act) {
      float2 t = ylL[(size_t)s << 3];        // yl row stride 16 floats = 8 float2
      r.x = t.x; r.y = t.y;
    }
    return r;
  };

  int j = beg + g;
  for (; j + 8 < end; j += 16) {             // 2 edges of this group: j, j+8
    int s0 = colA[j], s1 = colA[j + 8];
    f32x2 x0 = load(s0), x1 = load(s1);
    update(x0); update(x1);
  }
  if (j < end) update(load(colA[j]));

  // fixed combine tree across the 8 groups (deterministic)
  for (int o = 8; o <= 32; o <<= 1) {
    l     += __shfl_xor(l, o);
    acc.x += __shfl_xor(acc.x, o);
    acc.y += __shfl_xor(acc.y, o);
  }
  if (g == 0 && act) {
    float2 o;
    o.x = acc.x / l + bias[ch];
    o.y = acc.y / l + bias[ch + 1];
    *(float2*)(outp + (size_t)node * C2 + ch) = o;
  }
}

extern "C" void kernel_launch(void* const* d_in, const int* in_sizes, int n_in,
                              void* d_out, int out_size, void* d_ws, size_t ws_size,
                              hipStream_t stream) {
  const float* x    = (const float*)d_in[0];
  const int*   ei   = (const int*)d_in[1];
  const float* W1l  = (const float*)d_in[2];
  const float* W1r  = (const float*)d_in[3];
  const float* att1 = (const float*)d_in[4];
  const float* b1   = (const float*)d_in[5];
  const float* W2l  = (const float*)d_in[6];
  const float* W2r  = (const float*)d_in[7];
  const float* att2 = (const float*)d_in[8];
  const float* b2   = (const float*)d_in[9];
  float* out = (float*)d_out;

  char* ws = (char*)d_ws;
  size_t off = 0;
  auto take = [&](size_t bytes) -> char* {
    char* p = ws + off;
    off = (off + bytes + 511) & ~(size_t)511;
    return p;
  };
  unsigned short* Hlb = (unsigned short*)take((size_t)N_NODES * FDIM * sizeof(unsigned short)); // 25.6 MB
  unsigned short* Hrb = (unsigned short*)take((size_t)N_NODES * FDIM * sizeof(unsigned short)); // 25.6 MB
  unsigned short* Wt  = (unsigned short*)take((size_t)256 * 128 * sizeof(unsigned short));      // 64 KB
  float* yl      = (float*)take((size_t)N_NODES * YPAD * sizeof(float));   // 6.4 MB
  float* yr      = (float*)take((size_t)N_NODES * YPAD * sizeof(float));   // 6.4 MB
  int*   row_ptr = (int*)take((size_t)(N_NODES + 1) * sizeof(int));
  int*   colA    = (int*)take((size_t)E_TOT * sizeof(int));
  unsigned int* bkt = (unsigned int*)take((size_t)NBUK * BCAP * sizeof(unsigned int));  // 8.0 MB
  int*   bcur    = (int*)take(512);
  if (off > ws_size) return;

  k_prep_w <<<NWT, 256, 0, stream>>>(W1l, W1r, Wt, bcur);
  k_gc     <<<GB4 + NBB, 256, 0, stream>>>(x, Wt, Hlb, Hrb, ei, bcur, bkt);
  k_bkt    <<<NBUK, 256, 0, stream>>>(bcur, bkt, row_ptr, colA);
  k_agg1   <<<(N_NODES + 3) / 4, 256, 0, stream>>>(Hlb, Hrb, row_ptr, colA, att1, b1, W2l, W2r, yl, yr);
  k_agg2   <<<(N_NODES + 3) / 4, 256, 0, stream>>>(yl, yr, row_ptr, colA, att2, b2, out);
}

// Round 17
// 326.362 us; speedup vs baseline: 1.6346x; 1.0584x over previous
//
#include <hip/hip_runtime.h>

#define N_NODES 100000
#define E_EDGES 1600000
#define E_TOT   1700000   // edges + self loops
#define FDIM    128       // F_IN and HEADS*HID
#define C2      10        // classes
#define YPAD    16        // yl/yr row stride (one 64B line)
#define NEG     0.2f
#define LOG2E   1.44269504088896f
#define PCLAMP  80.0f

#define NWT     128                          // 32768 / 256
#define GB4     ((N_NODES + 255) / 256)      // 391 gemm blocks (64 rows/wave)
#define NBUK    196                          // dst>>9 buckets (<=512 nodes each)
#define BCAP    10240                        // per-bucket capacity (mean 8673 + 17 sigma)
#define NBB     ((E_TOT + 2047) / 2048)      // 831 bucket-scatter blocks

typedef __attribute__((ext_vector_type(8))) short short8;
typedef __attribute__((ext_vector_type(4))) float f32x4;
typedef __attribute__((ext_vector_type(2))) float f32x2;

// 16-lane / 8-lane row reductions via DPP (pure VALU, no LDS pipe)
template <int CTRL>
__device__ __forceinline__ float dpp_add(float x) {
  return x + __int_as_float(
      __builtin_amdgcn_update_dpp(0, __float_as_int(x), CTRL, 0xF, 0xF, true));
}
__device__ __forceinline__ float row16_sum(float p) {
  p = dpp_add<0xB1>(p);
  p = dpp_add<0x4E>(p);
  p = dpp_add<0x141>(p);
  p = dpp_add<0x140>(p);
  return p;
}
__device__ __forceinline__ float row8_sum(float p) {
  p = dpp_add<0xB1>(p);
  p = dpp_add<0x4E>(p);
  p = dpp_add<0x141>(p);
  return p;
}

// fp32 -> bf16 (round-nearest-even), and packed bf16x2 -> float2
__device__ __forceinline__ unsigned short f2bf(float f) {
  unsigned int u = __float_as_uint(f);
  u += 0x7FFFu + ((u >> 16) & 1u);
  return (unsigned short)(u >> 16);
}
__device__ __forceinline__ f32x2 up2v(unsigned int v) {
  f32x2 r;
  r.x = __uint_as_float(v << 16);
  r.y = __uint_as_float(v & 0xFFFF0000u);
  return r;
}

// adaptive-depth in-wave bitonic sort (lanes >= deg hold INT_MAX)
template <int KMAX>
__device__ __forceinline__ int bsort(int v, int lane) {
#pragma unroll
  for (int k = 2; k <= KMAX; k <<= 1) {
#pragma unroll
    for (int j = k >> 1; j > 0; j >>= 1) {
      int other = __shfl_xor(v, j);
      bool up = ((lane & k) == 0);
      bool lower = ((lane & j) == 0);
      int mn = min(v, other), mx = max(v, other);
      v = (lower == up) ? mn : mx;
    }
  }
  return v;
}

// ---------------- W1 transpose + bucket-cursor zeroing ----------------
__global__ __launch_bounds__(256) void k_prep_w(const float* __restrict__ W1l, const float* __restrict__ W1r,
                                                unsigned short* __restrict__ Wt, int* __restrict__ bcur) {
  int i = blockIdx.x * 256 + threadIdx.x;
  int n = i & 255, k = i >> 8;
  float v = (n < 128) ? W1l[k * 128 + n] : W1r[k * 128 + (n - 128)];
  Wt[n * 128 + k] = f2bf(v);   // B^T layout: row n, contiguous k
  if (blockIdx.x == 0) bcur[threadIdx.x] = 0;   // 256 >= NBUK
}

// ---------------- fused: Layer-1 GEMM (blocks < GB4) + coarse bucket-scatter (rest) ----------------
// Bucket-scatter: 2048-edge chunk, (src,dst) register-cached (single global read),
// LDS 196-bin histogram, ONE global atomic per (block,bucket), packed (lid<<17|src) writes.
__global__ __launch_bounds__(256) void k_gc(const float* __restrict__ x,
                                            const unsigned short* __restrict__ Wt,
                                            unsigned short* __restrict__ Hlb,
                                            unsigned short* __restrict__ Hrb,
                                            const int* __restrict__ ei, int* __restrict__ bcur,
                                            unsigned int* __restrict__ bkt) {
  __shared__ int lhist[NBUK], lbase[NBUK];
  int b = blockIdx.x;
  if (b >= GB4) {
    int t = threadIdx.x;
    int e0 = (b - GB4) * 2048;
    int e1 = min(e0 + 2048, E_TOT);
    if (t < NBUK) lhist[t] = 0;
    __syncthreads();
    int ss[8], ds[8];
#pragma unroll
    for (int i = 0; i < 8; i++) {
      int e = e0 + t + i * 256;
      int s = -1, d = -1;
      if (e < e1) {
        if (e < E_EDGES) { s = ei[e]; d = ei[E_EDGES + e]; }
        else { s = e - E_EDGES; d = s; }
        atomicAdd(&lhist[d >> 9], 1);
      }
      ss[i] = s; ds[i] = d;
    }
    __syncthreads();
    if (t < NBUK) { lbase[t] = atomicAdd(&bcur[t], lhist[t]); lhist[t] = 0; }
    __syncthreads();
#pragma unroll
    for (int i = 0; i < 8; i++) {
      int d = ds[i];
      if (d >= 0) {
        int lb = d >> 9;
        int pos = lbase[lb] + atomicAdd(&lhist[lb], 1);
        bkt[(size_t)lb * BCAP + pos] = ((unsigned)(d & 511) << 17) | (unsigned)ss[i];
      }
    }
    return;
  }
  int w = threadIdx.x >> 6, lane = threadIdx.x & 63;
  int m = lane & 15, quad = lane >> 4;
  int wrow0 = b * 256 + w * 64;
  short8 A[4][4];   // [row-group][k-chunk]
#pragma unroll
  for (int g = 0; g < 4; g++) {
    int arow = wrow0 + g * 16 + m;
    bool aok = arow < N_NODES;
    const float4* ap = (const float4*)(x + (size_t)arow * FDIM + quad * 8);
#pragma unroll
    for (int c = 0; c < 4; c++) {
      short8 a = {};
      if (aok) {
        float4 v0 = ap[c * 8 + 0];
        float4 v1 = ap[c * 8 + 1];
        a[0] = (short)f2bf(v0.x); a[1] = (short)f2bf(v0.y);
        a[2] = (short)f2bf(v0.z); a[3] = (short)f2bf(v0.w);
        a[4] = (short)f2bf(v1.x); a[5] = (short)f2bf(v1.y);
        a[6] = (short)f2bf(v1.z); a[7] = (short)f2bf(v1.w);
      }
      A[g][c] = a;
    }
  }

#pragma unroll
  for (int t0 = 0; t0 < 16; t0++) {
    const short8* bp = (const short8*)(Wt + (size_t)(t0 * 16 + m) * 128 + quad * 8);
    short8 B0 = bp[0], B1 = bp[4], B2 = bp[8], B3 = bp[12];
    int n0 = t0 * 16;
    unsigned short* dst = (n0 < 128) ? Hlb : Hrb;
    int col = (n0 < 128) ? n0 + m : (n0 - 128) + m;
#pragma unroll
    for (int g = 0; g < 4; g++) {
      f32x4 acc = {0.f, 0.f, 0.f, 0.f};
      acc = __builtin_amdgcn_mfma_f32_16x16x32_bf16(A[g][0], B0, acc, 0, 0, 0);
      acc = __builtin_amdgcn_mfma_f32_16x16x32_bf16(A[g][1], B1, acc, 0, 0, 0);
      acc = __builtin_amdgcn_mfma_f32_16x16x32_bf16(A[g][2], B2, acc, 0, 0, 0);
      acc = __builtin_amdgcn_mfma_f32_16x16x32_bf16(A[g][3], B3, acc, 0, 0, 0);
      int orow = wrow0 + g * 16 + quad * 4;
#pragma unroll
      for (int r = 0; r < 4; r++) {
        int row = orow + r;
        if (row < N_NODES) dst[(size_t)row * FDIM + col] = f2bf(acc[r]);
      }
    }
  }
}

// ---------------- fine CSR build: one block per bucket (<=512 nodes, ~8.7K edges) ----------------
__global__ __launch_bounds__(256) void k_bkt(const int* __restrict__ bcur,
                                             const unsigned int* __restrict__ bkt,
                                             int* __restrict__ row_ptr, int* __restrict__ colA) {
  __shared__ int eb[256];
  __shared__ int hist[512];
  __shared__ int pfx[512];
  __shared__ int sd[256];
  int b = blockIdx.x, t = threadIdx.x;
  // inclusive prefix over bucket sizes (redundant per block; 256 >= NBUK)
  eb[t] = (t < NBUK) ? bcur[t] : 0;
  __syncthreads();
  for (int o = 1; o < 256; o <<= 1) {
    int v = 0;
    if (t >= o) v = eb[t - o];
    __syncthreads();
    eb[t] += v;
    __syncthreads();
  }
  int ne = bcur[b];
  int base = eb[b] - ne;          // exclusive edge base of this bucket
  int node0 = b << 9;
  int nn = min(512, N_NODES - node0);
  hist[t] = 0; hist[t + 256] = 0;
  __syncthreads();
  const unsigned int* mybkt = bkt + (size_t)b * BCAP;
  for (int e = t; e < ne; e += 256)
    atomicAdd(&hist[mybkt[e] >> 17], 1);
  __syncthreads();
  // scan 512 bins (2 per thread + 256-wide Hillis-Steele)
  int b0 = 2 * t;
  int s0 = hist[b0], s1 = hist[b0 + 1];
  int ts = s0 + s1;
  sd[t] = ts; __syncthreads();
  for (int o = 1; o < 256; o <<= 1) {
    int v = 0;
    if (t >= o) v = sd[t - o];
    __syncthreads();
    sd[t] += v;
    __syncthreads();
  }
  int run = sd[t] - ts;           // exclusive partial
  pfx[b0] = run; pfx[b0 + 1] = run + s0;
  hist[b0] = 0; hist[b0 + 1] = 0;   // reuse as cursors
  __syncthreads();
  for (int i = t; i < nn; i += 256) row_ptr[node0 + i] = base + pfx[i];
  if (b == 0 && t == 0) row_ptr[N_NODES] = E_TOT;
  // scatter (order nondeterministic within row; agg1 sorts -> deterministic numerics)
  for (int e = t; e < ne; e += 256) {
    unsigned int u = mybkt[e];
    int lid = u >> 17;
    int pos = base + pfx[lid] + atomicAdd(&hist[lid], 1);
    colA[pos] = (int)(u & 0x1FFFFu);
  }
}

// ---------------- Layer-1 aggregation + in-wave CSR sort + fused layer-2 transform ----------------
// r15 champion + pre-scaled sidx (element offsets: saves one shift per edge).
__global__ __launch_bounds__(256) void k_agg1(const unsigned short* __restrict__ Hlb,
                                              const unsigned short* __restrict__ Hrb,
                                              const int* __restrict__ row_ptr, int* __restrict__ colA,
                                              const float* __restrict__ att, const float* __restrict__ bias,
                                              const float* __restrict__ W2l, const float* __restrict__ W2r,
                                              float* __restrict__ yl, float* __restrict__ yr) {
  __shared__ float hsh[4][FDIM];
  __shared__ int sidx[4][64];
  __shared__ float w2t[2][C2][132];   // transposed W2, +4 pad
  for (int i = threadIdx.x; i < FDIM * C2; i += 256) {
    int k = i / C2, cc = i - C2 * k;
    w2t[0][cc][k] = W2l[i];
    w2t[1][cc][k] = W2r[i];
  }
  __syncthreads();

  int w = threadIdx.x >> 6;
  int node = blockIdx.x * 4 + w;
  int lane = threadIdx.x & 63;
  int c0 = 2 * lane;
  const unsigned int* Hl32 = (const unsigned int*)Hlb;   // row = 64 uints
  const unsigned int* Hr32 = (const unsigned int*)Hrb;
  f32x2 xr = up2v(Hr32[((size_t)node << 6) + lane]);
  f32x2 av; av.x = att[c0] * LOG2E; av.y = att[c0 + 1] * LOG2E;
  int beg = row_ptr[node], end = row_ptr[node + 1];
  int deg = end - beg;
  bool small = deg <= 64;

  if (small) {
    int v = (lane < deg) ? colA[beg + lane] : 0x7FFFFFFF;
    if (deg <= 16)      v = bsort<16>(v, lane);
    else if (deg <= 32) v = bsort<32>(v, lane);
    else                v = bsort<64>(v, lane);
    sidx[w][lane] = v << 6;                 // PRE-SCALED element offset (row = 64 uints)
    if (lane < deg) colA[beg + lane] = v;   // sorted row (raw ids) for agg2
  } else {
    if (lane == 0) {
      for (int i = beg + 1; i < end; i++) {
        int vv = colA[i];
        int j = i - 1;
        while (j >= beg && colA[j] > vv) { colA[j + 1] = colA[j]; j--; }
        colA[j + 1] = vv;
      }
    }
    __threadfence_block();
  }

  float l = 0.f;
  f32x2 acc = {0.f, 0.f};
  auto update = [&](unsigned int vv) {
    f32x2 xl = up2v(vv);
    f32x2 t = xl + xr;                       // v_pk_add_f32
    f32x2 u = t * NEG;                       // v_pk_mul_f32
    t = __builtin_elementwise_max(t, u);     // v_pk_max_f32: leaky = max(t, 0.2t)
    f32x2 m = t * av;                        // v_pk_mul_f32
    float p = row16_sum(m.x + m.y);
    float ww = __builtin_amdgcn_exp2f(fminf(p, PCLAMP));
    l += ww;
    acc += xl * ww;                          // v_pk_fma_f32
  };

  if (small) {
    const int* si = sidx[w];
    int j = 0;
    for (; j + 8 <= deg; j += 8) {
      unsigned int v0 = Hl32[(size_t)(unsigned)(si[j + 0] + lane)];
      unsigned int v1 = Hl32[(size_t)(unsigned)(si[j + 1] + lane)];
      unsigned int v2 = Hl32[(size_t)(unsigned)(si[j + 2] + lane)];
      unsigned int v3 = Hl32[(size_t)(unsigned)(si[j + 3] + lane)];
      unsigned int v4 = Hl32[(size_t)(unsigned)(si[j + 4] + lane)];
      unsigned int v5 = Hl32[(size_t)(unsigned)(si[j + 5] + lane)];
      unsigned int v6 = Hl32[(size_t)(unsigned)(si[j + 6] + lane)];
      unsigned int v7 = Hl32[(size_t)(unsigned)(si[j + 7] + lane)];
      update(v0); update(v1); update(v2); update(v3);
      update(v4); update(v5); update(v6); update(v7);
    }
    for (; j + 2 <= deg; j += 2) {
      unsigned int v0 = Hl32[(size_t)(unsigned)(si[j + 0] + lane)];
      unsigned int v1 = Hl32[(size_t)(unsigned)(si[j + 1] + lane)];
      update(v0); update(v1);
    }
    if (j < deg) update(Hl32[(size_t)(unsigned)(si[j] + lane)]);
  } else {
    for (int j = beg; j < end; j++) update(Hl32[((size_t)colA[j] << 6) + lane]);
  }

  float inv = 1.f / l;
  float ox = fmaxf(fmaf(acc.x, inv, bias[c0]),     0.f);   // fused ReLU
  float oy = fmaxf(fmaf(acc.y, inv, bias[c0 + 1]), 0.f);
  hsh[w][c0] = ox; hsh[w][c0 + 1] = oy;
  // epilogue: 2 lanes per output (lane 2o: k4 0..15, lane 2o+1: k4 16..31), shfl combine
  if (lane < 4 * C2) {
    int o = lane >> 1;               // output 0..19
    int half = lane & 1;             // k-range half
    bool isl = o < C2;
    int cc = isl ? o : o - C2;
    const float4* wrow = (const float4*)&w2t[isl ? 0 : 1][cc][0];
    const float4* h4 = (const float4*)hsh[w];
    float a2 = 0.f;
    int k0 = half << 4;
#pragma unroll
    for (int k4 = 0; k4 < 16; k4++) {
      float4 hv = h4[k0 + k4];
      float4 wv = wrow[k0 + k4];
      a2 = fmaf(hv.x, wv.x, a2);
      a2 = fmaf(hv.y, wv.y, a2);
      a2 = fmaf(hv.z, wv.z, a2);
      a2 = fmaf(hv.w, wv.w, a2);
    }
    a2 += __shfl_xor(a2, 1);         // fixed tree: (low half)+(high half)
    if (half == 0) {
      float* Y = isl ? yl : yr;
      Y[(size_t)node * YPAD + cc] = a2;
    }
  }
}

// ---------------- Layer-2 aggregation: 1 wave/node, 8-way edge-parallel, 2 ch/lane packed ----------------
__global__ __launch_bounds__(256) void k_agg2(const float* __restrict__ yl, const float* __restrict__ yr,
                                              const int* __restrict__ row_ptr, const int* __restrict__ colA,
                                              const float* __restrict__ att, const float* __restrict__ bias,
                                              float* __restrict__ outp) {
  int w = threadIdx.x >> 6;
  int node = blockIdx.x * 4 + w;
  if (node >= N_NODES) return;
  int lane = threadIdx.x & 63;
  int ch = 2 * (lane & 7);     // channel pair this lane owns
  int g  = lane >> 3;          // edge-group 0..7
  bool act = ch < C2;
  f32x2 xr = {0.f, 0.f};
  f32x2 a2 = {0.f, 0.f};
  if (act) {
    const float2* yr2 = (const float2*)(yr + (size_t)node * YPAD);
    float2 t = yr2[lane & 7];
    xr.x = t.x; xr.y = t.y;
    a2.x = att[ch] * LOG2E; a2.y = att[ch + 1] * LOG2E;
  }
  int beg = row_ptr[node], end = row_ptr[node + 1];
  float l = 0.f;
  f32x2 acc = {0.f, 0.f};
  const float2* ylL = (const float2*)yl + (lane & 7);   // row s at (s<<3) float2 units

  auto update = [&](f32x2 xl) {
    f32x2 t = xl + xr;                       // v_pk_add_f32
    f32x2 u = t * NEG;                       // v_pk_mul_f32
    t = __builtin_elementwise_max(t, u);     // v_pk_max_f32
    f32x2 m = t * a2;                        // v_pk_mul_f32
    float p = row8_sum(m.x + m.y);           // 8-lane group reduce (inactive lanes add 0)
    float wgt = __builtin_amdgcn_exp2f(fminf(p, PCLAMP));
    l += wgt;
    acc += xl * wgt;                         // v_pk_fma_f32
  };
  auto load = [&](int s) -> f32x2 {
    f32x2 r = {0.f, 0.f};
    if (act) {
      float2 t = ylL[(size_t)s << 3];        // yl row stride 16 floats = 8 float2
      r.x = t.x; r.y = t.y;
    }
    return r;
  };

  int j = beg + g;
  for (; j + 8 < end; j += 16) {             // 2 edges of this group: j, j+8
    int s0 = colA[j], s1 = colA[j + 8];
    f32x2 x0 = load(s0), x1 = load(s1);
    update(x0); update(x1);
  }
  if (j < end) update(load(colA[j]));

  // fixed combine tree across the 8 groups (deterministic)
  for (int o = 8; o <= 32; o <<= 1) {
    l     += __shfl_xor(l, o);
    acc.x += __shfl_xor(acc.x, o);
    acc.y += __shfl_xor(acc.y, o);
  }
  if (g == 0 && act) {
    float2 o;
    o.x = acc.x / l + bias[ch];
    o.y = acc.y / l + bias[ch + 1];
    *(float2*)(outp + (size_t)node * C2 + ch) = o;
  }
}

extern "C" void kernel_launch(void* const* d_in, const int* in_sizes, int n_in,
                              void* d_out, int out_size, void* d_ws, size_t ws_size,
                              hipStream_t stream) {
  const float* x    = (const float*)d_in[0];
  const int*   ei   = (const int*)d_in[1];
  const float* W1l  = (const float*)d_in[2];
  const float* W1r  = (const float*)d_in[3];
  const float* att1 = (const float*)d_in[4];
  const float* b1   = (const float*)d_in[5];
  const float* W2l  = (const float*)d_in[6];
  const float* W2r  = (const float*)d_in[7];
  const float* att2 = (const float*)d_in[8];
  const float* b2   = (const float*)d_in[9];
  float* out = (float*)d_out;

  char* ws = (char*)d_ws;
  size_t off = 0;
  auto take = [&](size_t bytes) -> char* {
    char* p = ws + off;
    off = (off + bytes + 511) & ~(size_t)511;
    return p;
  };
  unsigned short* Hlb = (unsigned short*)take((size_t)N_NODES * FDIM * sizeof(unsigned short)); // 25.6 MB
  unsigned short* Hrb = (unsigned short*)take((size_t)N_NODES * FDIM * sizeof(unsigned short)); // 25.6 MB
  unsigned short* Wt  = (unsigned short*)take((size_t)256 * 128 * sizeof(unsigned short));      // 64 KB
  float* yl      = (float*)take((size_t)N_NODES * YPAD * sizeof(float));   // 6.4 MB
  float* yr      = (float*)take((size_t)N_NODES * YPAD * sizeof(float));   // 6.4 MB
  int*   row_ptr = (int*)take((size_t)(N_NODES + 1) * sizeof(int));
  int*   colA    = (int*)take((size_t)E_TOT * sizeof(int));
  unsigned int* bkt = (unsigned int*)take((size_t)NBUK * BCAP * sizeof(unsigned int));  // 8.0 MB
  int*   bcur    = (int*)take(1024);
  if (off > ws_size) return;

  k_prep_w <<<NWT, 256, 0, stream>>>(W1l, W1r, Wt, bcur);
  k_gc     <<<GB4 + NBB, 256, 0, stream>>>(x, Wt, Hlb, Hrb, ei, bcur, bkt);
  k_bkt    <<<NBUK, 256, 0, stream>>>(bcur, bkt, row_ptr, colA);
  k_agg1   <<<(N_NODES + 3) / 4, 256, 0, stream>>>(Hlb, Hrb, row_ptr, colA, att1, b1, W2l, W2r, yl, yr);
  k_agg2   <<<(N_NODES + 3) / 4, 256, 0, stream>>>(yl, yr, row_ptr, colA, att2, b2, out);
}

// Round 18
// 321.711 us; speedup vs baseline: 1.6582x; 1.0145x over previous
//
#include <hip/hip_runtime.h>

#define N_NODES 100000
#define E_EDGES 1600000
#define E_TOT   1700000   // edges + self loops
#define FDIM    128       // F_IN and HEADS*HID
#define C2      10        // classes
#define YPAD    16        // yl/yr row stride (one 64B line)
#define NEG     0.2f
#define LOG2E   1.44269504088896f
#define PCLAMP  80.0f

#define NWT     128                          // 32768 / 256
#define GB4     ((N_NODES + 255) / 256)      // 391 gemm blocks (64 rows/wave)
#define NBUK    196                          // dst>>9 buckets (<=512 nodes each)
#define BCAP    10240                        // per-bucket capacity (mean 8673 + 17 sigma)
#define NBB     ((E_TOT + 2047) / 2048)      // 831 bucket-scatter blocks

typedef __attribute__((ext_vector_type(8))) short short8;
typedef __attribute__((ext_vector_type(4))) float f32x4;
typedef __attribute__((ext_vector_type(2))) float f32x2;

// 16-lane / 8-lane row reductions via DPP (pure VALU, no LDS pipe)
template <int CTRL>
__device__ __forceinline__ float dpp_add(float x) {
  return x + __int_as_float(
      __builtin_amdgcn_update_dpp(0, __float_as_int(x), CTRL, 0xF, 0xF, true));
}
__device__ __forceinline__ float row16_sum(float p) {
  p = dpp_add<0xB1>(p);
  p = dpp_add<0x4E>(p);
  p = dpp_add<0x141>(p);
  p = dpp_add<0x140>(p);
  return p;
}
__device__ __forceinline__ float row8_sum(float p) {
  p = dpp_add<0xB1>(p);
  p = dpp_add<0x4E>(p);
  p = dpp_add<0x141>(p);
  return p;
}

// fp32 -> bf16 (round-nearest-even), and packed bf16x2 -> float2
__device__ __forceinline__ unsigned short f2bf(float f) {
  unsigned int u = __float_as_uint(f);
  u += 0x7FFFu + ((u >> 16) & 1u);
  return (unsigned short)(u >> 16);
}
__device__ __forceinline__ f32x2 up2v(unsigned int v) {
  f32x2 r;
  r.x = __uint_as_float(v << 16);
  r.y = __uint_as_float(v & 0xFFFF0000u);
  return r;
}

// adaptive-depth in-wave bitonic sort (lanes >= deg hold INT_MAX)
template <int KMAX>
__device__ __forceinline__ int bsort(int v, int lane) {
#pragma unroll
  for (int k = 2; k <= KMAX; k <<= 1) {
#pragma unroll
    for (int j = k >> 1; j > 0; j >>= 1) {
      int other = __shfl_xor(v, j);
      bool up = ((lane & k) == 0);
      bool lower = ((lane & j) == 0);
      int mn = min(v, other), mx = max(v, other);
      v = (lower == up) ? mn : mx;
    }
  }
  return v;
}

// ---------------- W1 transpose + bucket-cursor zeroing ----------------
__global__ __launch_bounds__(256) void k_prep_w(const float* __restrict__ W1l, const float* __restrict__ W1r,
                                                unsigned short* __restrict__ Wt, int* __restrict__ bcur) {
  int i = blockIdx.x * 256 + threadIdx.x;
  int n = i & 255, k = i >> 8;
  float v = (n < 128) ? W1l[k * 128 + n] : W1r[k * 128 + (n - 128)];
  Wt[n * 128 + k] = f2bf(v);   // B^T layout: row n, contiguous k
  if (blockIdx.x == 0) bcur[threadIdx.x] = 0;   // 256 >= NBUK
}

// ---------------- fused: Layer-1 GEMM (blocks < GB4) + coarse bucket-scatter (rest) ----------------
// Bucket pass: register-cached edges -> LDS histogram -> LDS counting-sort into a
// 2048-word staging buffer -> per-bucket COALESCED run flush (writes 109 MB -> ~26 MB).
__global__ __launch_bounds__(256) void k_gc(const float* __restrict__ x,
                                            const unsigned short* __restrict__ Wt,
                                            unsigned short* __restrict__ Hlb,
                                            unsigned short* __restrict__ Hrb,
                                            const int* __restrict__ ei, int* __restrict__ bcur,
                                            unsigned int* __restrict__ bkt) {
  __shared__ int lhist[NBUK], lbase[NBUK], lpfx[NBUK];
  __shared__ unsigned int stage[2048];
  int b = blockIdx.x;
  if (b >= GB4) {
    int t = threadIdx.x;
    int e0 = (b - GB4) * 2048;
    int e1 = min(e0 + 2048, E_TOT);
    if (t < NBUK) lhist[t] = 0;
    __syncthreads();
    int ss[8], ds[8];
#pragma unroll
    for (int i = 0; i < 8; i++) {
      int e = e0 + t + i * 256;
      int s = -1, d = -1;
      if (e < e1) {
        if (e < E_EDGES) { s = ei[e]; d = ei[E_EDGES + e]; }
        else { s = e - E_EDGES; d = s; }
        atomicAdd(&lhist[d >> 9], 1);
      }
      ss[i] = s; ds[i] = d;
    }
    __syncthreads();
    // exclusive scan of lhist (scratch = stage) + global reservation + cursor reset
    int* sc = (int*)stage;
    int hv = (t < NBUK) ? lhist[t] : 0;
    sc[t] = hv; __syncthreads();
    for (int o = 1; o < 256; o <<= 1) {
      int v = 0;
      if (t >= o) v = sc[t - o];
      __syncthreads();
      sc[t] += v;
      __syncthreads();
    }
    int incl = sc[t];
    __syncthreads();
    if (t < NBUK) {
      lpfx[t] = incl - hv;
      lbase[t] = atomicAdd(&bcur[t], hv);
      lhist[t] = 0;
    }
    __syncthreads();
    // counting-sort into LDS staging (bucket-ordered)
#pragma unroll
    for (int i = 0; i < 8; i++) {
      int d = ds[i];
      if (d >= 0) {
        int lb = d >> 9;
        int pos = lpfx[lb] + atomicAdd(&lhist[lb], 1);
        stage[pos] = ((unsigned)(d & 511) << 17) | (unsigned)ss[i];
      }
    }
    __syncthreads();
    // coalesced flush: wave w handles buckets w, w+4, ... (contiguous run per bucket)
    int wv = t >> 6, lane = t & 63;
    for (int lb = wv; lb < NBUK; lb += 4) {
      int cnt = lhist[lb];
      int pf = lpfx[lb];
      unsigned int* gp = bkt + (size_t)lb * BCAP + lbase[lb];
      for (int i = lane; i < cnt; i += 64) gp[i] = stage[pf + i];
    }
    return;
  }
  int w = threadIdx.x >> 6, lane = threadIdx.x & 63;
  int m = lane & 15, quad = lane >> 4;
  int wrow0 = b * 256 + w * 64;
  short8 A[4][4];   // [row-group][k-chunk]
#pragma unroll
  for (int g = 0; g < 4; g++) {
    int arow = wrow0 + g * 16 + m;
    bool aok = arow < N_NODES;
    const float4* ap = (const float4*)(x + (size_t)arow * FDIM + quad * 8);
#pragma unroll
    for (int c = 0; c < 4; c++) {
      short8 a = {};
      if (aok) {
        float4 v0 = ap[c * 8 + 0];
        float4 v1 = ap[c * 8 + 1];
        a[0] = (short)f2bf(v0.x); a[1] = (short)f2bf(v0.y);
        a[2] = (short)f2bf(v0.z); a[3] = (short)f2bf(v0.w);
        a[4] = (short)f2bf(v1.x); a[5] = (short)f2bf(v1.y);
        a[6] = (short)f2bf(v1.z); a[7] = (short)f2bf(v1.w);
      }
      A[g][c] = a;
    }
  }

#pragma unroll
  for (int t0 = 0; t0 < 16; t0++) {
    const short8* bp = (const short8*)(Wt + (size_t)(t0 * 16 + m) * 128 + quad * 8);
    short8 B0 = bp[0], B1 = bp[4], B2 = bp[8], B3 = bp[12];
    int n0 = t0 * 16;
    unsigned short* dst = (n0 < 128) ? Hlb : Hrb;
    int col = (n0 < 128) ? n0 + m : (n0 - 128) + m;
#pragma unroll
    for (int g = 0; g < 4; g++) {
      f32x4 acc = {0.f, 0.f, 0.f, 0.f};
      acc = __builtin_amdgcn_mfma_f32_16x16x32_bf16(A[g][0], B0, acc, 0, 0, 0);
      acc = __builtin_amdgcn_mfma_f32_16x16x32_bf16(A[g][1], B1, acc, 0, 0, 0);
      acc = __builtin_amdgcn_mfma_f32_16x16x32_bf16(A[g][2], B2, acc, 0, 0, 0);
      acc = __builtin_amdgcn_mfma_f32_16x16x32_bf16(A[g][3], B3, acc, 0, 0, 0);
      int orow = wrow0 + g * 16 + quad * 4;
#pragma unroll
      for (int r = 0; r < 4; r++) {
        int row = orow + r;
        if (row < N_NODES) dst[(size_t)row * FDIM + col] = f2bf(acc[r]);
      }
    }
  }
}

// ---------------- fine CSR build: one block per bucket (<=512 nodes, ~8.7K edges) ----------------
__global__ __launch_bounds__(256) void k_bkt(const int* __restrict__ bcur,
                                             const unsigned int* __restrict__ bkt,
                                             int* __restrict__ row_ptr, int* __restrict__ colA) {
  __shared__ int eb[256];
  __shared__ int hist[512];
  __shared__ int pfx[512];
  __shared__ int sd[256];
  int b = blockIdx.x, t = threadIdx.x;
  // inclusive prefix over bucket sizes (redundant per block; 256 >= NBUK)
  eb[t] = (t < NBUK) ? bcur[t] : 0;
  __syncthreads();
  for (int o = 1; o < 256; o <<= 1) {
    int v = 0;
    if (t >= o) v = eb[t - o];
    __syncthreads();
    eb[t] += v;
    __syncthreads();
  }
  int ne = bcur[b];
  int base = eb[b] - ne;          // exclusive edge base of this bucket
  int node0 = b << 9;
  int nn = min(512, N_NODES - node0);
  hist[t] = 0; hist[t + 256] = 0;
  __syncthreads();
  const unsigned int* mybkt = bkt + (size_t)b * BCAP;
  for (int e = t; e < ne; e += 256)
    atomicAdd(&hist[mybkt[e] >> 17], 1);
  __syncthreads();
  // scan 512 bins (2 per thread + 256-wide Hillis-Steele)
  int b0 = 2 * t;
  int s0 = hist[b0], s1 = hist[b0 + 1];
  int ts = s0 + s1;
  sd[t] = ts; __syncthreads();
  for (int o = 1; o < 256; o <<= 1) {
    int v = 0;
    if (t >= o) v = sd[t - o];
    __syncthreads();
    sd[t] += v;
    __syncthreads();
  }
  int run = sd[t] - ts;           // exclusive partial
  pfx[b0] = run; pfx[b0 + 1] = run + s0;
  hist[b0] = 0; hist[b0 + 1] = 0;   // reuse as cursors
  __syncthreads();
  for (int i = t; i < nn; i += 256) row_ptr[node0 + i] = base + pfx[i];
  if (b == 0 && t == 0) row_ptr[N_NODES] = E_TOT;
  // scatter (order nondeterministic within row; agg1 sorts -> deterministic numerics)
  for (int e = t; e < ne; e += 256) {
    unsigned int u = mybkt[e];
    int lid = u >> 17;
    int pos = base + pfx[lid] + atomicAdd(&hist[lid], 1);
    colA[pos] = (int)(u & 0x1FFFFu);
  }
}

// ---------------- Layer-1 aggregation + in-wave CSR sort + fused layer-2 transform ----------------
// r17 champion: adaptive sort + pre-scaled sidx + half-split epilogue (measured 120.0 us).
__global__ __launch_bounds__(256) void k_agg1(const unsigned short* __restrict__ Hlb,
                                              const unsigned short* __restrict__ Hrb,
                                              const int* __restrict__ row_ptr, int* __restrict__ colA,
                                              const float* __restrict__ att, const float* __restrict__ bias,
                                              const float* __restrict__ W2l, const float* __restrict__ W2r,
                                              float* __restrict__ yl, float* __restrict__ yr) {
  __shared__ float hsh[4][FDIM];
  __shared__ int sidx[4][64];
  __shared__ float w2t[2][C2][132];   // transposed W2, +4 pad
  for (int i = threadIdx.x; i < FDIM * C2; i += 256) {
    int k = i / C2, cc = i - C2 * k;
    w2t[0][cc][k] = W2l[i];
    w2t[1][cc][k] = W2r[i];
  }
  __syncthreads();

  int w = threadIdx.x >> 6;
  int node = blockIdx.x * 4 + w;
  int lane = threadIdx.x & 63;
  int c0 = 2 * lane;
  const unsigned int* Hl32 = (const unsigned int*)Hlb;   // row = 64 uints
  const unsigned int* Hr32 = (const unsigned int*)Hrb;
  f32x2 xr = up2v(Hr32[((size_t)node << 6) + lane]);
  f32x2 av; av.x = att[c0] * LOG2E; av.y = att[c0 + 1] * LOG2E;
  int beg = row_ptr[node], end = row_ptr[node + 1];
  int deg = end - beg;
  bool small = deg <= 64;

  if (small) {
    int v = (lane < deg) ? colA[beg + lane] : 0x7FFFFFFF;
    if (deg <= 16)      v = bsort<16>(v, lane);
    else if (deg <= 32) v = bsort<32>(v, lane);
    else                v = bsort<64>(v, lane);
    sidx[w][lane] = v << 6;                 // PRE-SCALED element offset (row = 64 uints)
    if (lane < deg) colA[beg + lane] = v;   // sorted row (raw ids) for agg2
  } else {
    if (lane == 0) {
      for (int i = beg + 1; i < end; i++) {
        int vv = colA[i];
        int j = i - 1;
        while (j >= beg && colA[j] > vv) { colA[j + 1] = colA[j]; j--; }
        colA[j + 1] = vv;
      }
    }
    __threadfence_block();
  }

  float l = 0.f;
  f32x2 acc = {0.f, 0.f};
  auto update = [&](unsigned int vv) {
    f32x2 xl = up2v(vv);
    f32x2 t = xl + xr;                       // v_pk_add_f32
    f32x2 u = t * NEG;                       // v_pk_mul_f32
    t = __builtin_elementwise_max(t, u);     // v_pk_max_f32: leaky = max(t, 0.2t)
    f32x2 m = t * av;                        // v_pk_mul_f32
    float p = row16_sum(m.x + m.y);
    float ww = __builtin_amdgcn_exp2f(fminf(p, PCLAMP));
    l += ww;
    acc += xl * ww;                          // v_pk_fma_f32
  };

  if (small) {
    const int* si = sidx[w];
    int j = 0;
    for (; j + 8 <= deg; j += 8) {
      unsigned int v0 = Hl32[(size_t)(unsigned)(si[j + 0] + lane)];
      unsigned int v1 = Hl32[(size_t)(unsigned)(si[j + 1] + lane)];
      unsigned int v2 = Hl32[(size_t)(unsigned)(si[j + 2] + lane)];
      unsigned int v3 = Hl32[(size_t)(unsigned)(si[j + 3] + lane)];
      unsigned int v4 = Hl32[(size_t)(unsigned)(si[j + 4] + lane)];
      unsigned int v5 = Hl32[(size_t)(unsigned)(si[j + 5] + lane)];
      unsigned int v6 = Hl32[(size_t)(unsigned)(si[j + 6] + lane)];
      unsigned int v7 = Hl32[(size_t)(unsigned)(si[j + 7] + lane)];
      update(v0); update(v1); update(v2); update(v3);
      update(v4); update(v5); update(v6); update(v7);
    }
    for (; j + 2 <= deg; j += 2) {
      unsigned int v0 = Hl32[(size_t)(unsigned)(si[j + 0] + lane)];
      unsigned int v1 = Hl32[(size_t)(unsigned)(si[j + 1] + lane)];
      update(v0); update(v1);
    }
    if (j < deg) update(Hl32[(size_t)(unsigned)(si[j] + lane)]);
  } else {
    for (int j = beg; j < end; j++) update(Hl32[((size_t)colA[j] << 6) + lane]);
  }

  float inv = 1.f / l;
  float ox = fmaxf(fmaf(acc.x, inv, bias[c0]),     0.f);   // fused ReLU
  float oy = fmaxf(fmaf(acc.y, inv, bias[c0 + 1]), 0.f);
  hsh[w][c0] = ox; hsh[w][c0 + 1] = oy;
  // epilogue: 2 lanes per output (lane 2o: k4 0..15, lane 2o+1: k4 16..31), shfl combine
  if (lane < 4 * C2) {
    int o = lane >> 1;               // output 0..19
    int half = lane & 1;             // k-range half
    bool isl = o < C2;
    int cc = isl ? o : o - C2;
    const float4* wrow = (const float4*)&w2t[isl ? 0 : 1][cc][0];
    const float4* h4 = (const float4*)hsh[w];
    float a2 = 0.f;
    int k0 = half << 4;
#pragma unroll
    for (int k4 = 0; k4 < 16; k4++) {
      float4 hv = h4[k0 + k4];
      float4 wv = wrow[k0 + k4];
      a2 = fmaf(hv.x, wv.x, a2);
      a2 = fmaf(hv.y, wv.y, a2);
      a2 = fmaf(hv.z, wv.z, a2);
      a2 = fmaf(hv.w, wv.w, a2);
    }
    a2 += __shfl_xor(a2, 1);         // fixed tree: (low half)+(high half)
    if (half == 0) {
      float* Y = isl ? yl : yr;
      Y[(size_t)node * YPAD + cc] = a2;
    }
  }
}

// ---------------- Layer-2 aggregation: 1 wave/node, 8-way edge-parallel, 2 ch/lane packed ----------------
__global__ __launch_bounds__(256) void k_agg2(const float* __restrict__ yl, const float* __restrict__ yr,
                                              const int* __restrict__ row_ptr, const int* __restrict__ colA,
                                              const float* __restrict__ att, const float* __restrict__ bias,
                                              float* __restrict__ outp) {
  int w = threadIdx.x >> 6;
  int node = blockIdx.x * 4 + w;
  if (node >= N_NODES) return;
  int lane = threadIdx.x & 63;
  int ch = 2 * (lane & 7);     // channel pair this lane owns
  int g  = lane >> 3;          // edge-group 0..7
  bool act = ch < C2;
  f32x2 xr = {0.f, 0.f};
  f32x2 a2 = {0.f, 0.f};
  if (act) {
    const float2* yr2 = (const float2*)(yr + (size_t)node * YPAD);
    float2 t = yr2[lane & 7];
    xr.x = t.x; xr.y = t.y;
    a2.x = att[ch] * LOG2E; a2.y = att[ch + 1] * LOG2E;
  }
  int beg = row_ptr[node], end = row_ptr[node + 1];
  float l = 0.f;
  f32x2 acc = {0.f, 0.f};
  const float2* ylL = (const float2*)yl + (lane & 7);   // row s at (s<<3) float2 units

  auto update = [&](f32x2 xl) {
    f32x2 t = xl + xr;                       // v_pk_add_f32
    f32x2 u = t * NEG;                       // v_pk_mul_f32
    t = __builtin_elementwise_max(t, u);     // v_pk_max_f32
    f32x2 m = t * a2;                        // v_pk_mul_f32
    float p = row8_sum(m.x + m.y);           // 8-lane group reduce (inactive lanes add 0)
    float wgt = __builtin_amdgcn_exp2f(fminf(p, PCLAMP));
    l += wgt;
    acc += xl * wgt;                         // v_pk_fma_f32
  };
  auto load = [&](int s) -> f32x2 {
    f32x2 r = {0.f, 0.f};
    if (act) {
      float2 t = ylL[(size_t)s << 3];        // yl row stride 16 floats = 8 float2
      r.x = t.x; r.y = t.y;
    }
    return r;
  };

  int j = beg + g;
  for (; j + 8 < end; j += 16) {             // 2 edges of this group: j, j+8
    int s0 = colA[j], s1 = colA[j + 8];
    f32x2 x0 = load(s0), x1 = load(s1);
    update(x0); update(x1);
  }
  if (j < end) update(load(colA[j]));

  // fixed combine tree across the 8 groups (deterministic)
  for (int o = 8; o <= 32; o <<= 1) {
    l     += __shfl_xor(l, o);
    acc.x += __shfl_xor(acc.x, o);
    acc.y += __shfl_xor(acc.y, o);
  }
  if (g == 0 && act) {
    float2 o;
    o.x = acc.x / l + bias[ch];
    o.y = acc.y / l + bias[ch + 1];
    *(float2*)(outp + (size_t)node * C2 + ch) = o;
  }
}

extern "C" void kernel_launch(void* const* d_in, const int* in_sizes, int n_in,
                              void* d_out, int out_size, void* d_ws, size_t ws_size,
                              hipStream_t stream) {
  const float* x    = (const float*)d_in[0];
  const int*   ei   = (const int*)d_in[1];
  const float* W1l  = (const float*)d_in[2];
  const float* W1r  = (const float*)d_in[3];
  const float* att1 = (const float*)d_in[4];
  const float* b1   = (const float*)d_in[5];
  const float* W2l  = (const float*)d_in[6];
  const float* W2r  = (const float*)d_in[7];
  const float* att2 = (const float*)d_in[8];
  const float* b2   = (const float*)d_in[9];
  float* out = (float*)d_out;

  char* ws = (char*)d_ws;
  size_t off = 0;
  auto take = [&](size_t bytes) -> char* {
    char* p = ws + off;
    off = (off + bytes + 511) & ~(size_t)511;
    return p;
  };
  unsigned short* Hlb = (unsigned short*)take((size_t)N_NODES * FDIM * sizeof(unsigned short)); // 25.6 MB
  unsigned short* Hrb = (unsigned short*)take((size_t)N_NODES * FDIM * sizeof(unsigned short)); // 25.6 MB
  unsigned short* Wt  = (unsigned short*)take((size_t)256 * 128 * sizeof(unsigned short));      // 64 KB
  float* yl      = (float*)take((size_t)N_NODES * YPAD * sizeof(float));   // 6.4 MB
  float* yr      = (float*)take((size_t)N_NODES * YPAD * sizeof(float));   // 6.4 MB
  int*   row_ptr = (int*)take((size_t)(N_NODES + 1) * sizeof(int));
  int*   colA    = (int*)take((size_t)E_TOT * sizeof(int));
  unsigned int* bkt = (unsigned int*)take((size_t)NBUK * BCAP * sizeof(unsigned int));  // 8.0 MB
  int*   bcur    = (int*)take(1024);
  if (off > ws_size) return;

  k_prep_w <<<NWT, 256, 0, stream>>>(W1l, W1r, Wt, bcur);
  k_gc     <<<GB4 + NBB, 256, 0, stream>>>(x, Wt, Hlb, Hrb, ei, bcur, bkt);
  k_bkt    <<<NBUK, 256, 0, stream>>>(bcur, bkt, row_ptr, colA);
  k_agg1   <<<(N_NODES + 3) / 4, 256, 0, stream>>>(Hlb, Hrb, row_ptr, colA, att1, b1, W2l, W2r, yl, yr);
  k_agg2   <<<(N_NODES + 3) / 4, 256, 0, stream>>>(yl, yr, row_ptr, colA, att2, b2, out);
}